// Round 5
// baseline (327.974 us; speedup 1.0000x reference)
//
#include <hip/hip_runtime.h>

#define B_   4
#define S_   256
#define E_   256
#define H_   8
#define LD_  128
#define N_   65536
#define NC_  2

typedef __attribute__((ext_vector_type(8))) short s8v;   // 8 bf16
typedef __attribute__((ext_vector_type(4))) float f32x4;

// RNE f32->bf16 via v_cvt_pk_bf16_f32 (identical rounding to integer RNE emu)
__device__ __forceinline__ short f2bf(float f) {
  unsigned u;
  asm("v_cvt_pk_bf16_f32 %0, %1, %2" : "=v"(u) : "v"(f), "v"(f));
  return (short)u;
}
__device__ __forceinline__ float bf2f(short s) {
  union { float f; unsigned u; } v; v.u = ((unsigned)(unsigned short)s) << 16;
  return v.f;
}
__device__ __forceinline__ s8v pack8(float4 a, float4 b) {
  union { s8v s; unsigned u[4]; } r;
  asm("v_cvt_pk_bf16_f32 %0, %1, %2" : "=v"(r.u[0]) : "v"(a.x), "v"(a.y));
  asm("v_cvt_pk_bf16_f32 %0, %1, %2" : "=v"(r.u[1]) : "v"(a.z), "v"(a.w));
  asm("v_cvt_pk_bf16_f32 %0, %1, %2" : "=v"(r.u[2]) : "v"(b.x), "v"(b.y));
  asm("v_cvt_pk_bf16_f32 %0, %1, %2" : "=v"(r.u[3]) : "v"(b.z), "v"(b.w));
  return r.s;
}

// ---------------------------------------------------------------------------
// prep_k: block-roles:
//   bid <  768          : weight convert / split + bn fold (ipw, w2, w3)
//   768 <= bid <= 1024  : ids fill
//   1025 <= bid <= 2048 : pos-MLP + gl^T add -> Xhi/Xlo
//   bid >= 2049         : M = W2b @ opw (fp32) -> Mh/Ml split; g0 = W2b @ opb
// ---------------------------------------------------------------------------
__global__ __launch_bounds__(256) void prep_k(
    const int* __restrict__ npc, int* __restrict__ ids,
    const float* __restrict__ ipw, const float* __restrict__ opw,
    const float* __restrict__ opb,
    const float* __restrict__ w2, const float* __restrict__ w3,
    const float* __restrict__ b2, const float* __restrict__ g2,
    const float* __restrict__ be2, const float* __restrict__ mu2,
    const float* __restrict__ va2,
    const float* __restrict__ b3, const float* __restrict__ g3,
    const float* __restrict__ be3, const float* __restrict__ mu3,
    const float* __restrict__ va3,
    short* __restrict__ iph, short* __restrict__ ipl,
    short* __restrict__ Mh, short* __restrict__ Ml,
    float* __restrict__ g0v,
    short* __restrict__ w2bf, short* __restrict__ w3bf,
    float* __restrict__ sc2, float* __restrict__ sh2,
    float* __restrict__ sc3, float* __restrict__ sh3,
    const float* __restrict__ gl, const float* __restrict__ cen,
    const float* __restrict__ fc1w, const float* __restrict__ fc1b,
    const float* __restrict__ fc2w, const float* __restrict__ fc2b,
    short* __restrict__ Xhi, short* __restrict__ Xlo) {
  __shared__ int red[256];
  __shared__ float hsh[16];
  __shared__ float wrow[256];
  __shared__ float gred[256];
  int bid = blockIdx.x, t = threadIdx.x;
  if (bid < 768) {
    int i = bid * 256 + t;
    if (i < 196608) {
      float v = ipw[i]; short h = f2bf(v);
      iph[i] = h; ipl[i] = f2bf(v - bf2f(h));
    }
    if (i < 49152) w2bf[i] = f2bf(w2[i]);
    if (i < 8192)  w3bf[i] = f2bf(w3[i]);
    if (i < 128) {
      float sc = g2[i] * rsqrtf(va2[i] + 1e-5f);
      sc2[i] = sc; sh2[i] = (b2[i] - mu2[i]) * sc + be2[i];
    }
    if (i < 64) {
      float sc = g3[i] * rsqrtf(va3[i] + 1e-5f);
      sc3[i] = sc; sh3[i] = (b3[i] - mu3[i]) * sc + be3[i];
    }
  } else if (bid <= 1024) {
    int s = bid - 768;   // 0..256
    int val = (s == 256) ? npc[t] : ((t < s) ? npc[t] : 0);
    red[t] = val;
    __syncthreads();
    for (int off = 128; off > 0; off >>= 1) {
      if (t < off) red[t] += red[t + off];
      __syncthreads();
    }
    int st = red[0];
    if (s < 256) {
      int en = st + npc[s]; if (en > N_) en = N_;
      for (int n = st + t; n < en; n += 256) ids[n] = s;
    } else {
      for (int n = st + t; n < N_; n += 256) ids[n] = 255;
    }
  } else if (bid <= 2048) {
    int bs = bid - 1025;   // 0..1023
    int b = bs >> 8, s = bs & 255;
    if (t < 16) {
      float c0 = cen[bs * 2 + 0], c1 = cen[bs * 2 + 1];
      float v = c0 * fc1w[2 * t] + c1 * fc1w[2 * t + 1] + fc1b[t];
      hsh[t] = (v >= 0.f) ? v : 0.01f * v;
    }
    __syncthreads();
    float p = fc2b[t];
#pragma unroll
    for (int j = 0; j < 16; j++) p += hsh[j] * fc2w[t * 16 + j];
    float v = gl[((size_t)s * B_ + b) * E_ + t] + p;
    short h = f2bf(v);
    Xhi[(size_t)bs * E_ + t] = h;
    Xlo[(size_t)bs * E_ + t] = f2bf(v - bf2f(h));
  } else {
    // M[c][e] = sum_k W2b[c][k] * opw[k][e];  W2b[c][k] = w2[c*384 + 128 + k]
    int c = bid - 2049;   // 0..127
    wrow[t] = w2[c * 384 + 128 + t];
    gred[t] = 0.f;
    __syncthreads();
    float acc = 0.f;
#pragma unroll 8
    for (int k = 0; k < 256; k++) acc += wrow[k] * opw[(size_t)k * 256 + t];
    short h = f2bf(acc);
    Mh[(size_t)c * 256 + t] = h;
    Ml[(size_t)c * 256 + t] = f2bf(acc - bf2f(h));
    // g0[c] = sum_k W2b[c][k] * opb[k]  (tree reduce, deterministic)
    gred[t] = wrow[t] * opb[t];
    __syncthreads();
    for (int off = 128; off > 0; off >>= 1) {
      if (t < off) gred[t] += gred[t + off];
      __syncthreads();
    }
    if (t == 0) g0v[c] = gred[0];
  }
}

// ---------------------------------------------------------------------------
// bf16x3 MFMA GEMM (qkv): C = (Ah+Al)(Wh+Wl)^T + bias -> fp32. 64x64 tiles.
// ---------------------------------------------------------------------------
__global__ __launch_bounds__(256) void gemm_x3_k(
    const short* __restrict__ Ah, const short* __restrict__ Al,
    const short* __restrict__ Wh, const short* __restrict__ Wl,
    const float* __restrict__ bias, float* __restrict__ Cf,
    int M, int N, int K) {
  __shared__ __align__(16) short gs[18432];
  const int AH = 0, AL = 4608, WH = 9216, WL = 13824;
  int t = threadIdx.x;
  int row0 = blockIdx.x * 64, col0 = blockIdx.y * 64;
  int w = t >> 6, l = t & 63, quad = l >> 4, lr = l & 15;
  int m0 = w * 16;
  int ar = t >> 2, aq = (t & 3) * 16;
  f32x4 acc[4];
#pragma unroll
  for (int i = 0; i < 4; i++) acc[i] = (f32x4)(0.f);

  for (int kc = 0; kc < K; kc += 64) {
    __syncthreads();
    {
      size_t ra = (size_t)(row0 + ar) * K + kc + aq;
      size_t rw = (size_t)(col0 + ar) * K + kc + aq;
      *(s8v*)&gs[AH + ar * 72 + aq]     = *(const s8v*)&Ah[ra];
      *(s8v*)&gs[AH + ar * 72 + aq + 8] = *(const s8v*)&Ah[ra + 8];
      *(s8v*)&gs[AL + ar * 72 + aq]     = *(const s8v*)&Al[ra];
      *(s8v*)&gs[AL + ar * 72 + aq + 8] = *(const s8v*)&Al[ra + 8];
      *(s8v*)&gs[WH + ar * 72 + aq]     = *(const s8v*)&Wh[rw];
      *(s8v*)&gs[WH + ar * 72 + aq + 8] = *(const s8v*)&Wh[rw + 8];
      *(s8v*)&gs[WL + ar * 72 + aq]     = *(const s8v*)&Wl[rw];
      *(s8v*)&gs[WL + ar * 72 + aq + 8] = *(const s8v*)&Wl[rw + 8];
    }
    __syncthreads();
#pragma unroll
    for (int ks = 0; ks < 2; ks++) {
      int ko = ks * 32 + quad * 8;
      s8v ah = *(const s8v*)&gs[AH + (m0 + lr) * 72 + ko];
      s8v al = *(const s8v*)&gs[AL + (m0 + lr) * 72 + ko];
#pragma unroll
      for (int ct = 0; ct < 4; ct++) {
        s8v bh = *(const s8v*)&gs[WH + (ct * 16 + lr) * 72 + ko];
        s8v bl = *(const s8v*)&gs[WL + (ct * 16 + lr) * 72 + ko];
        acc[ct] = __builtin_amdgcn_mfma_f32_16x16x32_bf16(ah, bh, acc[ct], 0, 0, 0);
        acc[ct] = __builtin_amdgcn_mfma_f32_16x16x32_bf16(al, bh, acc[ct], 0, 0, 0);
        acc[ct] = __builtin_amdgcn_mfma_f32_16x16x32_bf16(ah, bl, acc[ct], 0, 0, 0);
      }
    }
  }
#pragma unroll
  for (int ct = 0; ct < 4; ct++) {
    int c = col0 + ct * 16 + lr;
    float bb = bias[c];
#pragma unroll
    for (int rg = 0; rg < 4; rg++) {
      int r = row0 + m0 + quad * 4 + rg;
      Cf[(size_t)r * N + c] = acc[ct][rg] + bb;
    }
  }
}

// ---------------------------------------------------------------------------
// gk_k: G[1024][128] = (Chi+Clo) @ (Mh+Ml)^T + g0  (bf16x3, fp32 out).
// Replaces opgemm_k + gbf_k via M = W2b @ opw precomputed in prep.
// 64x32 tiles, grid (16,4).
// ---------------------------------------------------------------------------
__global__ __launch_bounds__(256) void gk_k(
    const short* __restrict__ Ah, const short* __restrict__ Al,
    const short* __restrict__ Wh, const short* __restrict__ Wl,
    const float* __restrict__ g0v, float* __restrict__ G) {
  __shared__ __align__(16) short gs[13824];
  const int AH = 0, AL = 4608, WH = 9216, WL = 11520;
  int t = threadIdx.x;
  int row0 = blockIdx.x * 64, col0 = blockIdx.y * 32;
  int w = t >> 6, l = t & 63, quad = l >> 4, lr = l & 15;
  int m0 = w * 16;
  int ar = t >> 2, aq = (t & 3) * 16;
  int wr = t >> 3, wq = (t & 7) * 8;
  f32x4 acc[2];
#pragma unroll
  for (int i = 0; i < 2; i++) acc[i] = (f32x4)(0.f);

  for (int kc = 0; kc < 256; kc += 64) {
    __syncthreads();
    {
      size_t ra = (size_t)(row0 + ar) * 256 + kc + aq;
      size_t rw = (size_t)(col0 + wr) * 256 + kc + wq;
      *(s8v*)&gs[AH + ar * 72 + aq]     = *(const s8v*)&Ah[ra];
      *(s8v*)&gs[AH + ar * 72 + aq + 8] = *(const s8v*)&Ah[ra + 8];
      *(s8v*)&gs[AL + ar * 72 + aq]     = *(const s8v*)&Al[ra];
      *(s8v*)&gs[AL + ar * 72 + aq + 8] = *(const s8v*)&Al[ra + 8];
      *(s8v*)&gs[WH + wr * 72 + wq]     = *(const s8v*)&Wh[rw];
      *(s8v*)&gs[WL + wr * 72 + wq]     = *(const s8v*)&Wl[rw];
    }
    __syncthreads();
#pragma unroll
    for (int ks = 0; ks < 2; ks++) {
      int ko = ks * 32 + quad * 8;
      s8v ah = *(const s8v*)&gs[AH + (m0 + lr) * 72 + ko];
      s8v al = *(const s8v*)&gs[AL + (m0 + lr) * 72 + ko];
#pragma unroll
      for (int ct = 0; ct < 2; ct++) {
        s8v bh = *(const s8v*)&gs[WH + (ct * 16 + lr) * 72 + ko];
        s8v bl = *(const s8v*)&gs[WL + (ct * 16 + lr) * 72 + ko];
        acc[ct] = __builtin_amdgcn_mfma_f32_16x16x32_bf16(ah, bh, acc[ct], 0, 0, 0);
        acc[ct] = __builtin_amdgcn_mfma_f32_16x16x32_bf16(al, bh, acc[ct], 0, 0, 0);
        acc[ct] = __builtin_amdgcn_mfma_f32_16x16x32_bf16(ah, bl, acc[ct], 0, 0, 0);
      }
    }
  }
#pragma unroll
  for (int ct = 0; ct < 2; ct++) {
    int c = col0 + ct * 16 + lr;
    float bb = g0v[c];
#pragma unroll
    for (int rg = 0; rg < 4; rg++) {
      int r = row0 + m0 + quad * 4 + rg;
      G[(size_t)r * 128 + c] = acc[ct][rg] + bb;
    }
  }
}

// ---------------------------------------------------------------------------
// attention (unchanged)
// ---------------------------------------------------------------------------
__global__ __launch_bounds__(256) void attn_k(const float* __restrict__ qkv,
                                              short* __restrict__ Chi,
                                              short* __restrict__ Clo) {
  int bid = blockIdx.x;
  int qt = bid & 7, h = (bid >> 3) & 7, b = bid >> 6;
  __shared__ __align__(16) float smem[16384];
  float* Kx = smem;
  float* Vx = smem + 8192;
  int t = threadIdx.x;
#pragma unroll
  for (int i = 0; i < 8; i++) {
    int row = i * 32 + (t >> 3);
    int d4 = (t & 7) * 4;
    const float* base = qkv + (size_t)(b * S_ + row) * 768 + h * 32 + d4;
    *(float4*)&Kx[row * 32 + d4] = *(const float4*)(base + 256);
    *(float4*)&Vx[row * 32 + d4] = *(const float4*)(base + 512);
  }
  int r = t & 31, g = t >> 5;
  float q[32];
  {
    const float* qb = qkv + (size_t)(b * S_ + qt * 32 + r) * 768 + h * 32;
#pragma unroll
    for (int d4 = 0; d4 < 32; d4 += 4) {
      float4 v = *(const float4*)(qb + d4);
      q[d4] = v.x; q[d4 + 1] = v.y; q[d4 + 2] = v.z; q[d4 + 3] = v.w;
    }
  }
  __syncthreads();
  const float scale = 0.17677669529663687f;
  int kk0 = g * 32;
  float sc[32];
  float m = -1e30f;
#pragma unroll
  for (int kk = 0; kk < 32; kk++) {
    const float* kr = &Kx[(kk0 + kk) * 32];
    float4 a = (float4){0.f, 0.f, 0.f, 0.f};
#pragma unroll
    for (int d4 = 0; d4 < 32; d4 += 4) {
      float4 kv = *(const float4*)(kr + d4);
      a.x += q[d4] * kv.x; a.y += q[d4 + 1] * kv.y;
      a.z += q[d4 + 2] * kv.z; a.w += q[d4 + 3] * kv.w;
    }
    float s = ((a.x + a.y) + (a.z + a.w)) * scale;
    sc[kk] = s;
    m = fmaxf(m, s);
  }
  float lsum = 0.f;
  float ctx[32];
#pragma unroll
  for (int d = 0; d < 32; d++) ctx[d] = 0.f;
#pragma unroll
  for (int kk = 0; kk < 32; kk++) {
    const float* vr = &Vx[(kk0 + kk) * 32];
    float p = __expf(sc[kk] - m);
    lsum += p;
#pragma unroll
    for (int d4 = 0; d4 < 32; d4 += 4) {
      float4 vv = *(const float4*)(vr + d4);
      ctx[d4] += p * vv.x; ctx[d4 + 1] += p * vv.y;
      ctx[d4 + 2] += p * vv.z; ctx[d4 + 3] += p * vv.w;
    }
  }
  __syncthreads();
  float* ctxbuf = smem;
  float* mbuf = smem + 8192;
  float* lbuf = smem + 8448;
  mbuf[g * 32 + r] = m;
  lbuf[g * 32 + r] = lsum;
#pragma unroll
  for (int d = 0; d < 32; d++)
    ctxbuf[(g * 32 + r) * 32 + ((d + r) & 31)] = ctx[d];
  __syncthreads();
  int r2 = t & 31, dq = t >> 5;
  float M = -1e30f;
#pragma unroll
  for (int gg = 0; gg < 8; gg++) M = fmaxf(M, mbuf[gg * 32 + r2]);
  float wg[8]; float L = 0.f;
#pragma unroll
  for (int gg = 0; gg < 8; gg++) {
    wg[gg] = __expf(mbuf[gg * 32 + r2] - M);
    L += lbuf[gg * 32 + r2] * wg[gg];
  }
  float invL = 1.f / L;
  size_t base = (size_t)(b * S_ + qt * 32 + r2) * E_ + h * 32;
#pragma unroll
  for (int dd = 0; dd < 4; dd++) {
    int d = dq * 4 + dd;
    float o = 0.f;
#pragma unroll
    for (int gg = 0; gg < 8; gg++)
      o += ctxbuf[(gg * 32 + r2) * 32 + ((d + r2) & 31)] * wg[gg];
    o *= invL;
    short hi = f2bf(o);
    Chi[base + d] = hi;
    Clo[base + d] = f2bf(o - bf2f(hi));
  }
}

// ---------------------------------------------------------------------------
// conv_fused v5: 128-pt blocks, NO A-staging, 3 barriers, 4 blocks/CU.
//   - conv2 A-fragments built directly from global lo (2x float4 + cvt_pk):
//     bit-identical bf16 values to the staged path, but no stage phase, no
//     barrier #1, no vmcnt drain before compute -> one big pipelined epoch.
//   - W2/W3 fragments direct from global (L1/L2-resident).
//   - uniform-G fast path (ids[n0]==ids[n0+127]); gather fallback.
//   - LDS: H2 [128][136] (34816 B); H3 [128][72] overlays H2.
// ---------------------------------------------------------------------------
__global__ __launch_bounds__(256, 4) void conv_fused_k(
    const float* __restrict__ lo, const float* __restrict__ G,
    const int* __restrict__ ids,
    const short* __restrict__ w2bf, const short* __restrict__ w3bf,
    const float* __restrict__ sc2, const float* __restrict__ sh2,
    const float* __restrict__ sc3, const float* __restrict__ sh3,
    const float* __restrict__ w4, const float* __restrict__ b4,
    float* __restrict__ out) {
  __shared__ __align__(16) short smem[17408];   // 34816 B (H2, H3 overlay)
  __shared__ int lds_ids[128];
  int t = threadIdx.x;
  int bid = blockIdx.x;
  int b = bid >> 9;
  int n0 = (bid & 511) << 7;
  int w = t >> 6, l = t & 63;
  int quad = l >> 4, lr = l & 15;
  int rh = w & 1, chh = w >> 1;

  // ---- G fast path: block-uniform cluster id ----
  int id0 = ids[n0], id127 = ids[n0 + 127];
  bool uni = (id0 == id127);
  float gseed[4];
  {
    const float* gr = &G[((size_t)b * 256 + id0) * 128 + 64 * chh + lr];
#pragma unroll
    for (int ct = 0; ct < 4; ct++) gseed[ct] = gr[16 * ct];
  }
  if (!uni) {
    if (t < 128) lds_ids[t] = ids[n0 + t];
    __syncthreads();   // uni is block-uniform -> barrier is uniform
  }

  // ---- conv2: 128 pts x 128 ch, K=128; A and W both direct from global ----
  const float* lob = &lo[((size_t)(b * N_ + n0)) * LD_];
  f32x4 acc2[4][4];
#pragma unroll
  for (int i = 0; i < 4; i++)
#pragma unroll
    for (int j = 0; j < 4; j++) acc2[i][j] = (f32x4)(0.f);
#pragma unroll
  for (int ks = 0; ks < 4; ks++) {
    int ko = ks * 32 + quad * 8;
    s8v af[4], bfr[4];
#pragma unroll
    for (int mt = 0; mt < 4; mt++) {
      int p = 64 * rh + 16 * mt + lr;
      const float* ap = lob + (size_t)p * LD_ + ko;
      float4 x = *(const float4*)ap;
      float4 y = *(const float4*)(ap + 4);
      af[mt] = pack8(x, y);
    }
#pragma unroll
    for (int ct = 0; ct < 4; ct++)
      bfr[ct] = *(const s8v*)&w2bf[(size_t)(64 * chh + 16 * ct + lr) * 384 + ko];
#pragma unroll
    for (int mt = 0; mt < 4; mt++)
#pragma unroll
      for (int ct = 0; ct < 4; ct++)
        acc2[mt][ct] = __builtin_amdgcn_mfma_f32_16x16x32_bf16(af[mt], bfr[ct], acc2[mt][ct], 0, 0, 0);
  }

  // ---- bn2 + relu (+G) -> H2 [128][136] ----
  size_t gbase = (size_t)b * 256 * 128;
#pragma unroll
  for (int ct = 0; ct < 4; ct++) {
    int c = 64 * chh + 16 * ct + lr;
    float sc = sc2[c], sh = sh2[c];
    float gsh = fmaf(gseed[ct], sc, sh);
#pragma unroll
    for (int mt = 0; mt < 4; mt++)
#pragma unroll
      for (int rg = 0; rg < 4; rg++) {
        int p = 64 * rh + 16 * mt + 4 * quad + rg;
        float z;
        if (uni) {
          z = fmaf(acc2[mt][ct][rg], sc, gsh);
        } else {
          float gv = G[gbase + (size_t)lds_ids[p] * 128 + c];
          z = fmaf(acc2[mt][ct][rg] + gv, sc, sh);
        }
        smem[p * 136 + c] = f2bf(fmaxf(z, 0.f));
      }
  }
  __syncthreads();   // #1: H2 complete

  // ---- conv3: 128 pts x 64 ch, K=128; wave w -> rows 32w..32w+31 ----
  f32x4 acc3[2][4];
#pragma unroll
  for (int i = 0; i < 2; i++)
#pragma unroll
    for (int j = 0; j < 4; j++) acc3[i][j] = (f32x4)(0.f);
#pragma unroll
  for (int ks = 0; ks < 4; ks++) {
    int ko = ks * 32 + quad * 8;
    s8v af2[2], bf3[4];
#pragma unroll
    for (int mt = 0; mt < 2; mt++)
      af2[mt] = *(const s8v*)&smem[(32 * w + 16 * mt + lr) * 136 + ko];
#pragma unroll
    for (int ct = 0; ct < 4; ct++)
      bf3[ct] = *(const s8v*)&w3bf[(size_t)(16 * ct + lr) * 128 + ko];
#pragma unroll
    for (int mt = 0; mt < 2; mt++)
#pragma unroll
      for (int ct = 0; ct < 4; ct++)
        acc3[mt][ct] = __builtin_amdgcn_mfma_f32_16x16x32_bf16(af2[mt], bf3[ct], acc3[mt][ct], 0, 0, 0);
  }
  __syncthreads();   // #2: all H2 reads done -> H3 may overlay

  // ---- bn3 + relu -> H3 [128][72] ----
#pragma unroll
  for (int ct = 0; ct < 4; ct++) {
    int c = 16 * ct + lr;
    float sc = sc3[c], sh = sh3[c];
#pragma unroll
    for (int mt = 0; mt < 2; mt++)
#pragma unroll
      for (int rg = 0; rg < 4; rg++) {
        int p = 32 * w + 16 * mt + 4 * quad + rg;
        float z = acc3[mt][ct][rg] * sc + sh;
        smem[p * 72 + c] = f2bf(fmaxf(z, 0.f));
      }
  }
  __syncthreads();   // #3: H3 complete

  // ---- conv4 (fp32 scalar, NC=2): 256 threads, 128 pts x 2 ch ----
  {
    int c = t >> 7, p = t & 127;
    float s = b4[c];
#pragma unroll
    for (int j = 0; j < 8; j++) {
      s8v hv = *(const s8v*)&smem[p * 72 + j * 8];
#pragma unroll
      for (int e = 0; e < 8; e++)
        s += bf2f(hv[e]) * w4[c * 64 + j * 8 + e];
    }
    out[((size_t)b * NC_ + c) * N_ + n0 + p] = s;
  }
}

// ---------------------------------------------------------------------------
extern "C" void kernel_launch(void* const* d_in, const int* in_sizes, int n_in,
                              void* d_out, int out_size, void* d_ws, size_t ws_size,
                              hipStream_t stream) {
  const float* gl   = (const float*)d_in[0];
  const float* lo   = (const float*)d_in[1];
  const float* cen  = (const float*)d_in[2];
  const int*   npc  = (const int*)d_in[3];
  const float* fc1w = (const float*)d_in[4];
  const float* fc1b = (const float*)d_in[5];
  const float* fc2w = (const float*)d_in[6];
  const float* fc2b = (const float*)d_in[7];
  const float* ipw  = (const float*)d_in[8];
  const float* ipb  = (const float*)d_in[9];
  const float* opw  = (const float*)d_in[10];
  const float* opb  = (const float*)d_in[11];
  const float* w2   = (const float*)d_in[12];
  const float* b2   = (const float*)d_in[13];
  const float* g2   = (const float*)d_in[14];
  const float* be2  = (const float*)d_in[15];
  const float* mu2  = (const float*)d_in[16];
  const float* va2  = (const float*)d_in[17];
  const float* w3   = (const float*)d_in[18];
  const float* b3   = (const float*)d_in[19];
  const float* g3   = (const float*)d_in[20];
  const float* be3  = (const float*)d_in[21];
  const float* mu3  = (const float*)d_in[22];
  const float* va3  = (const float*)d_in[23];
  const float* w4   = (const float*)d_in[24];
  const float* b4   = (const float*)d_in[25];

  char* ws = (char*)d_ws;
  float* qkv  = (float*)(ws);                  // 3,145,728
  short* Xhi  = (short*)(ws + 3145728);        // 524,288
  short* Xlo  = (short*)(ws + 3670016);
  short* Chi  = (short*)(ws + 4194304);
  short* Clo  = (short*)(ws + 4718592);
  float* G    = (float*)(ws + 5242880);        // 524,288 (B,256,128) fp32
  short* iph  = (short*)(ws + 5767168);        // 393,216
  short* ipl  = (short*)(ws + 6160384);
  short* Mh   = (short*)(ws + 6553600);        // 65,536
  short* Ml   = (short*)(ws + 6684672);        // 65,536
  short* w2bf = (short*)(ws + 6815744);        // 98,304
  short* w3bf = (short*)(ws + 6914048);        // 16,384
  int*   ids  = (int*)  (ws + 6930432);        // 262,144
  float* sc2  = (float*)(ws + 7192576);
  float* sh2  = (float*)(ws + 7193088);
  float* sc3  = (float*)(ws + 7193600);
  float* sh3  = (float*)(ws + 7193856);
  float* g0v  = (float*)(ws + 7194112);        // 512
  float* out  = (float*)d_out;

  prep_k<<<2177, 256, 0, stream>>>(npc, ids, ipw, opw, opb, w2, w3,
                                   b2, g2, be2, mu2, va2,
                                   b3, g3, be3, mu3, va3,
                                   iph, ipl, Mh, Ml, g0v, w2bf, w3bf,
                                   sc2, sh2, sc3, sh3,
                                   gl, cen, fc1w, fc1b, fc2w, fc2b, Xhi, Xlo);
  gemm_x3_k<<<dim3(16, 12), 256, 0, stream>>>(Xhi, Xlo, iph, ipl, ipb,
                                              qkv, B_ * S_, 768, E_);
  attn_k<<<B_ * H_ * 8, 256, 0, stream>>>(qkv, Chi, Clo);
  gk_k<<<dim3(16, 4), 256, 0, stream>>>(Chi, Clo, Mh, Ml, g0v, G);
  conv_fused_k<<<B_ * (N_ / 128), 256, 0, stream>>>(
      lo, G, ids, w2bf, w3bf, sc2, sh2, sc3, sh3, w4, b4, out);
}

// Round 6
// 311.103 us; speedup vs baseline: 1.0542x; 1.0542x over previous
//
#include <hip/hip_runtime.h>

#define B_   4
#define S_   256
#define E_   256
#define H_   8
#define LD_  128
#define N_   65536
#define NC_  2

typedef __attribute__((ext_vector_type(8))) short s8v;   // 8 bf16
typedef __attribute__((ext_vector_type(4))) float f32x4;

// RNE f32->bf16 via v_cvt_pk_bf16_f32 (identical rounding to integer RNE emu)
__device__ __forceinline__ short f2bf(float f) {
  unsigned u;
  asm("v_cvt_pk_bf16_f32 %0, %1, %2" : "=v"(u) : "v"(f), "v"(f));
  return (short)u;
}
__device__ __forceinline__ float bf2f(short s) {
  union { float f; unsigned u; } v; v.u = ((unsigned)(unsigned short)s) << 16;
  return v.f;
}
__device__ __forceinline__ s8v pack8(float4 a, float4 b) {
  union { s8v s; unsigned u[4]; } r;
  asm("v_cvt_pk_bf16_f32 %0, %1, %2" : "=v"(r.u[0]) : "v"(a.x), "v"(a.y));
  asm("v_cvt_pk_bf16_f32 %0, %1, %2" : "=v"(r.u[1]) : "v"(a.z), "v"(a.w));
  asm("v_cvt_pk_bf16_f32 %0, %1, %2" : "=v"(r.u[2]) : "v"(b.x), "v"(b.y));
  asm("v_cvt_pk_bf16_f32 %0, %1, %2" : "=v"(r.u[3]) : "v"(b.z), "v"(b.w));
  return r.s;
}

// ---------------------------------------------------------------------------
// prep_k: block-roles:
//   bid <  768          : weight convert / split + bn fold (ipw, w2, w3)
//   768 <= bid <= 1024  : ids fill
//   1025 <= bid <= 2048 : pos-MLP + gl^T add -> Xhi/Xlo
//   bid >= 2049         : M = W2b @ opw (fp32) -> Mh/Ml split; g0 = W2b @ opb
// ---------------------------------------------------------------------------
__global__ __launch_bounds__(256) void prep_k(
    const int* __restrict__ npc, int* __restrict__ ids,
    const float* __restrict__ ipw, const float* __restrict__ opw,
    const float* __restrict__ opb,
    const float* __restrict__ w2, const float* __restrict__ w3,
    const float* __restrict__ b2, const float* __restrict__ g2,
    const float* __restrict__ be2, const float* __restrict__ mu2,
    const float* __restrict__ va2,
    const float* __restrict__ b3, const float* __restrict__ g3,
    const float* __restrict__ be3, const float* __restrict__ mu3,
    const float* __restrict__ va3,
    short* __restrict__ iph, short* __restrict__ ipl,
    short* __restrict__ Mh, short* __restrict__ Ml,
    float* __restrict__ g0v,
    short* __restrict__ w2bf, short* __restrict__ w3bf,
    float* __restrict__ sc2, float* __restrict__ sh2,
    float* __restrict__ sc3, float* __restrict__ sh3,
    const float* __restrict__ gl, const float* __restrict__ cen,
    const float* __restrict__ fc1w, const float* __restrict__ fc1b,
    const float* __restrict__ fc2w, const float* __restrict__ fc2b,
    short* __restrict__ Xhi, short* __restrict__ Xlo) {
  __shared__ int red[256];
  __shared__ float hsh[16];
  __shared__ float wrow[256];
  __shared__ float gred[256];
  int bid = blockIdx.x, t = threadIdx.x;
  if (bid < 768) {
    int i = bid * 256 + t;
    if (i < 196608) {
      float v = ipw[i]; short h = f2bf(v);
      iph[i] = h; ipl[i] = f2bf(v - bf2f(h));
    }
    if (i < 49152) w2bf[i] = f2bf(w2[i]);
    if (i < 8192)  w3bf[i] = f2bf(w3[i]);
    if (i < 128) {
      float sc = g2[i] * rsqrtf(va2[i] + 1e-5f);
      sc2[i] = sc; sh2[i] = (b2[i] - mu2[i]) * sc + be2[i];
    }
    if (i < 64) {
      float sc = g3[i] * rsqrtf(va3[i] + 1e-5f);
      sc3[i] = sc; sh3[i] = (b3[i] - mu3[i]) * sc + be3[i];
    }
  } else if (bid <= 1024) {
    int s = bid - 768;   // 0..256
    int val = (s == 256) ? npc[t] : ((t < s) ? npc[t] : 0);
    red[t] = val;
    __syncthreads();
    for (int off = 128; off > 0; off >>= 1) {
      if (t < off) red[t] += red[t + off];
      __syncthreads();
    }
    int st = red[0];
    if (s < 256) {
      int en = st + npc[s]; if (en > N_) en = N_;
      for (int n = st + t; n < en; n += 256) ids[n] = s;
    } else {
      for (int n = st + t; n < N_; n += 256) ids[n] = 255;
    }
  } else if (bid <= 2048) {
    int bs = bid - 1025;   // 0..1023
    int b = bs >> 8, s = bs & 255;
    if (t < 16) {
      float c0 = cen[bs * 2 + 0], c1 = cen[bs * 2 + 1];
      float v = c0 * fc1w[2 * t] + c1 * fc1w[2 * t + 1] + fc1b[t];
      hsh[t] = (v >= 0.f) ? v : 0.01f * v;
    }
    __syncthreads();
    float p = fc2b[t];
#pragma unroll
    for (int j = 0; j < 16; j++) p += hsh[j] * fc2w[t * 16 + j];
    float v = gl[((size_t)s * B_ + b) * E_ + t] + p;
    short h = f2bf(v);
    Xhi[(size_t)bs * E_ + t] = h;
    Xlo[(size_t)bs * E_ + t] = f2bf(v - bf2f(h));
  } else {
    // M[c][e] = sum_k W2b[c][k] * opw[k][e];  W2b[c][k] = w2[c*384 + 128 + k]
    int c = bid - 2049;   // 0..127
    wrow[t] = w2[c * 384 + 128 + t];
    gred[t] = 0.f;
    __syncthreads();
    float acc = 0.f;
#pragma unroll 8
    for (int k = 0; k < 256; k++) acc += wrow[k] * opw[(size_t)k * 256 + t];
    short h = f2bf(acc);
    Mh[(size_t)c * 256 + t] = h;
    Ml[(size_t)c * 256 + t] = f2bf(acc - bf2f(h));
    // g0[c] = sum_k W2b[c][k] * opb[k]  (tree reduce, deterministic)
    gred[t] = wrow[t] * opb[t];
    __syncthreads();
    for (int off = 128; off > 0; off >>= 1) {
      if (t < off) gred[t] += gred[t + off];
      __syncthreads();
    }
    if (t == 0) g0v[c] = gred[0];
  }
}

// ---------------------------------------------------------------------------
// bf16x3 MFMA GEMM (qkv): C = (Ah+Al)(Wh+Wl)^T + bias -> fp32. 64x64 tiles.
// ---------------------------------------------------------------------------
__global__ __launch_bounds__(256) void gemm_x3_k(
    const short* __restrict__ Ah, const short* __restrict__ Al,
    const short* __restrict__ Wh, const short* __restrict__ Wl,
    const float* __restrict__ bias, float* __restrict__ Cf,
    int M, int N, int K) {
  __shared__ __align__(16) short gs[18432];
  const int AH = 0, AL = 4608, WH = 9216, WL = 13824;
  int t = threadIdx.x;
  int row0 = blockIdx.x * 64, col0 = blockIdx.y * 64;
  int w = t >> 6, l = t & 63, quad = l >> 4, lr = l & 15;
  int m0 = w * 16;
  int ar = t >> 2, aq = (t & 3) * 16;
  f32x4 acc[4];
#pragma unroll
  for (int i = 0; i < 4; i++) acc[i] = (f32x4)(0.f);

  for (int kc = 0; kc < K; kc += 64) {
    __syncthreads();
    {
      size_t ra = (size_t)(row0 + ar) * K + kc + aq;
      size_t rw = (size_t)(col0 + ar) * K + kc + aq;
      *(s8v*)&gs[AH + ar * 72 + aq]     = *(const s8v*)&Ah[ra];
      *(s8v*)&gs[AH + ar * 72 + aq + 8] = *(const s8v*)&Ah[ra + 8];
      *(s8v*)&gs[AL + ar * 72 + aq]     = *(const s8v*)&Al[ra];
      *(s8v*)&gs[AL + ar * 72 + aq + 8] = *(const s8v*)&Al[ra + 8];
      *(s8v*)&gs[WH + ar * 72 + aq]     = *(const s8v*)&Wh[rw];
      *(s8v*)&gs[WH + ar * 72 + aq + 8] = *(const s8v*)&Wh[rw + 8];
      *(s8v*)&gs[WL + ar * 72 + aq]     = *(const s8v*)&Wl[rw];
      *(s8v*)&gs[WL + ar * 72 + aq + 8] = *(const s8v*)&Wl[rw + 8];
    }
    __syncthreads();
#pragma unroll
    for (int ks = 0; ks < 2; ks++) {
      int ko = ks * 32 + quad * 8;
      s8v ah = *(const s8v*)&gs[AH + (m0 + lr) * 72 + ko];
      s8v al = *(const s8v*)&gs[AL + (m0 + lr) * 72 + ko];
#pragma unroll
      for (int ct = 0; ct < 4; ct++) {
        s8v bh = *(const s8v*)&gs[WH + (ct * 16 + lr) * 72 + ko];
        s8v bl = *(const s8v*)&gs[WL + (ct * 16 + lr) * 72 + ko];
        acc[ct] = __builtin_amdgcn_mfma_f32_16x16x32_bf16(ah, bh, acc[ct], 0, 0, 0);
        acc[ct] = __builtin_amdgcn_mfma_f32_16x16x32_bf16(al, bh, acc[ct], 0, 0, 0);
        acc[ct] = __builtin_amdgcn_mfma_f32_16x16x32_bf16(ah, bl, acc[ct], 0, 0, 0);
      }
    }
  }
#pragma unroll
  for (int ct = 0; ct < 4; ct++) {
    int c = col0 + ct * 16 + lr;
    float bb = bias[c];
#pragma unroll
    for (int rg = 0; rg < 4; rg++) {
      int r = row0 + m0 + quad * 4 + rg;
      Cf[(size_t)r * N + c] = acc[ct][rg] + bb;
    }
  }
}

// ---------------------------------------------------------------------------
// gk_k: G[1024][128] = (Chi+Clo) @ (Mh+Ml)^T + g0  (bf16x3, fp32 out).
// 64x32 tiles, grid (16,4).
// ---------------------------------------------------------------------------
__global__ __launch_bounds__(256) void gk_k(
    const short* __restrict__ Ah, const short* __restrict__ Al,
    const short* __restrict__ Wh, const short* __restrict__ Wl,
    const float* __restrict__ g0v, float* __restrict__ G) {
  __shared__ __align__(16) short gs[13824];
  const int AH = 0, AL = 4608, WH = 9216, WL = 11520;
  int t = threadIdx.x;
  int row0 = blockIdx.x * 64, col0 = blockIdx.y * 32;
  int w = t >> 6, l = t & 63, quad = l >> 4, lr = l & 15;
  int m0 = w * 16;
  int ar = t >> 2, aq = (t & 3) * 16;
  int wr = t >> 3, wq = (t & 7) * 8;
  f32x4 acc[2];
#pragma unroll
  for (int i = 0; i < 2; i++) acc[i] = (f32x4)(0.f);

  for (int kc = 0; kc < 256; kc += 64) {
    __syncthreads();
    {
      size_t ra = (size_t)(row0 + ar) * 256 + kc + aq;
      size_t rw = (size_t)(col0 + wr) * 256 + kc + wq;
      *(s8v*)&gs[AH + ar * 72 + aq]     = *(const s8v*)&Ah[ra];
      *(s8v*)&gs[AH + ar * 72 + aq + 8] = *(const s8v*)&Ah[ra + 8];
      *(s8v*)&gs[AL + ar * 72 + aq]     = *(const s8v*)&Al[ra];
      *(s8v*)&gs[AL + ar * 72 + aq + 8] = *(const s8v*)&Al[ra + 8];
      *(s8v*)&gs[WH + wr * 72 + wq]     = *(const s8v*)&Wh[rw];
      *(s8v*)&gs[WL + wr * 72 + wq]     = *(const s8v*)&Wl[rw];
    }
    __syncthreads();
#pragma unroll
    for (int ks = 0; ks < 2; ks++) {
      int ko = ks * 32 + quad * 8;
      s8v ah = *(const s8v*)&gs[AH + (m0 + lr) * 72 + ko];
      s8v al = *(const s8v*)&gs[AL + (m0 + lr) * 72 + ko];
#pragma unroll
      for (int ct = 0; ct < 2; ct++) {
        s8v bh = *(const s8v*)&gs[WH + (ct * 16 + lr) * 72 + ko];
        s8v bl = *(const s8v*)&gs[WL + (ct * 16 + lr) * 72 + ko];
        acc[ct] = __builtin_amdgcn_mfma_f32_16x16x32_bf16(ah, bh, acc[ct], 0, 0, 0);
        acc[ct] = __builtin_amdgcn_mfma_f32_16x16x32_bf16(al, bh, acc[ct], 0, 0, 0);
        acc[ct] = __builtin_amdgcn_mfma_f32_16x16x32_bf16(ah, bl, acc[ct], 0, 0, 0);
      }
    }
  }
#pragma unroll
  for (int ct = 0; ct < 2; ct++) {
    int c = col0 + ct * 16 + lr;
    float bb = g0v[c];
#pragma unroll
    for (int rg = 0; rg < 4; rg++) {
      int r = row0 + m0 + quad * 4 + rg;
      G[(size_t)r * 128 + c] = acc[ct][rg] + bb;
    }
  }
}

// ---------------------------------------------------------------------------
// attention (unchanged)
// ---------------------------------------------------------------------------
__global__ __launch_bounds__(256) void attn_k(const float* __restrict__ qkv,
                                              short* __restrict__ Chi,
                                              short* __restrict__ Clo) {
  int bid = blockIdx.x;
  int qt = bid & 7, h = (bid >> 3) & 7, b = bid >> 6;
  __shared__ __align__(16) float smem[16384];
  float* Kx = smem;
  float* Vx = smem + 8192;
  int t = threadIdx.x;
#pragma unroll
  for (int i = 0; i < 8; i++) {
    int row = i * 32 + (t >> 3);
    int d4 = (t & 7) * 4;
    const float* base = qkv + (size_t)(b * S_ + row) * 768 + h * 32 + d4;
    *(float4*)&Kx[row * 32 + d4] = *(const float4*)(base + 256);
    *(float4*)&Vx[row * 32 + d4] = *(const float4*)(base + 512);
  }
  int r = t & 31, g = t >> 5;
  float q[32];
  {
    const float* qb = qkv + (size_t)(b * S_ + qt * 32 + r) * 768 + h * 32;
#pragma unroll
    for (int d4 = 0; d4 < 32; d4 += 4) {
      float4 v = *(const float4*)(qb + d4);
      q[d4] = v.x; q[d4 + 1] = v.y; q[d4 + 2] = v.z; q[d4 + 3] = v.w;
    }
  }
  __syncthreads();
  const float scale = 0.17677669529663687f;
  int kk0 = g * 32;
  float sc[32];
  float m = -1e30f;
#pragma unroll
  for (int kk = 0; kk < 32; kk++) {
    const float* kr = &Kx[(kk0 + kk) * 32];
    float4 a = (float4){0.f, 0.f, 0.f, 0.f};
#pragma unroll
    for (int d4 = 0; d4 < 32; d4 += 4) {
      float4 kv = *(const float4*)(kr + d4);
      a.x += q[d4] * kv.x; a.y += q[d4 + 1] * kv.y;
      a.z += q[d4 + 2] * kv.z; a.w += q[d4 + 3] * kv.w;
    }
    float s = ((a.x + a.y) + (a.z + a.w)) * scale;
    sc[kk] = s;
    m = fmaxf(m, s);
  }
  float lsum = 0.f;
  float ctx[32];
#pragma unroll
  for (int d = 0; d < 32; d++) ctx[d] = 0.f;
#pragma unroll
  for (int kk = 0; kk < 32; kk++) {
    const float* vr = &Vx[(kk0 + kk) * 32];
    float p = __expf(sc[kk] - m);
    lsum += p;
#pragma unroll
    for (int d4 = 0; d4 < 32; d4 += 4) {
      float4 vv = *(const float4*)(vr + d4);
      ctx[d4] += p * vv.x; ctx[d4 + 1] += p * vv.y;
      ctx[d4 + 2] += p * vv.z; ctx[d4 + 3] += p * vv.w;
    }
  }
  __syncthreads();
  float* ctxbuf = smem;
  float* mbuf = smem + 8192;
  float* lbuf = smem + 8448;
  mbuf[g * 32 + r] = m;
  lbuf[g * 32 + r] = lsum;
#pragma unroll
  for (int d = 0; d < 32; d++)
    ctxbuf[(g * 32 + r) * 32 + ((d + r) & 31)] = ctx[d];
  __syncthreads();
  int r2 = t & 31, dq = t >> 5;
  float M = -1e30f;
#pragma unroll
  for (int gg = 0; gg < 8; gg++) M = fmaxf(M, mbuf[gg * 32 + r2]);
  float wg[8]; float L = 0.f;
#pragma unroll
  for (int gg = 0; gg < 8; gg++) {
    wg[gg] = __expf(mbuf[gg * 32 + r2] - M);
    L += lbuf[gg * 32 + r2] * wg[gg];
  }
  float invL = 1.f / L;
  size_t base = (size_t)(b * S_ + qt * 32 + r2) * E_ + h * 32;
#pragma unroll
  for (int dd = 0; dd < 4; dd++) {
    int d = dq * 4 + dd;
    float o = 0.f;
#pragma unroll
    for (int gg = 0; gg < 8; gg++)
      o += ctxbuf[(gg * 32 + r2) * 32 + ((d + r2) & 31)] * wg[gg];
    o *= invL;
    short hi = f2bf(o);
    Chi[base + d] = hi;
    Clo[base + d] = f2bf(o - bf2f(hi));
  }
}

// ---------------------------------------------------------------------------
// conv_fused v6 = round-2 v2 (measured best: 83us, 60 VGPR, no spill)
//                 + uniform-cluster G fast path.
//   - A (lo tile) staged full-K once: [128][136] bf16 (two pf[8] chunks).
//   - W2a / W3 fragments DIRECT from global (L1/L2-resident).
//   - G residual as MFMA C-in seed; uni blocks (ids[n0]==ids[n0+127], always
//     true for np_cluster==P) seed from 4 loads; else per-point gather.
//   - H2 [128][136] overlays A after conv2; H3 [128][72] overlays H2.
// LDS 35.3 KB -> 4 blocks/CU.
// ---------------------------------------------------------------------------
__global__ __launch_bounds__(256, 4) void conv_fused_k(
    const float* __restrict__ lo, const float* __restrict__ G,
    const int* __restrict__ ids,
    const short* __restrict__ w2bf, const short* __restrict__ w3bf,
    const float* __restrict__ sc2, const float* __restrict__ sh2,
    const float* __restrict__ sc3, const float* __restrict__ sh3,
    const float* __restrict__ w4, const float* __restrict__ b4,
    float* __restrict__ out) {
  __shared__ __align__(16) short smem[17408];   // 34816 B, overlaid 3 ways
  __shared__ int lds_ids[128];
  int t = threadIdx.x;
  int bid = blockIdx.x;
  int b = bid >> 9;
  int n0 = (bid & 511) << 7;
  int w = t >> 6, l = t & 63;
  int quad = l >> 4, lr = l & 15;
  int mh = w & 1, chh = w >> 1;
  int ar = t >> 1, akh = (t & 1) * 64;
  const float* lob = &lo[((size_t)b * N_ + n0 + ar) * LD_ + akh];

  // ---- G fast-path loads (issued first; latency hides under staging) ----
  int id0 = ids[n0], id127 = ids[n0 + 127];
  bool uni = (id0 == id127);
  float gseed[4];
  {
    const float* gr = &G[((size_t)b * 256 + id0) * 128 + 64 * chh + lr];
#pragma unroll
    for (int ct = 0; ct < 4; ct++) gseed[ct] = gr[16 * ct];
  }
  if (t < 128) lds_ids[t] = ids[n0 + t];

  // ---- stage A full-K (64 floats/thread, two 32-float chunks) ----
  {
    float4 pf[8];
#pragma unroll
    for (int j = 0; j < 8; j++) pf[j] = *(const float4*)(lob + j * 4);
#pragma unroll
    for (int j = 0; j < 4; j++)
      *(s8v*)&smem[ar * 136 + akh + j * 8] = pack8(pf[2 * j], pf[2 * j + 1]);
#pragma unroll
    for (int j = 0; j < 8; j++) pf[j] = *(const float4*)(lob + 32 + j * 4);
#pragma unroll
    for (int j = 0; j < 4; j++)
      *(s8v*)&smem[ar * 136 + akh + 32 + j * 8] = pack8(pf[2 * j], pf[2 * j + 1]);
  }
  __syncthreads();   // #1

  // ---- seed acc2 with G residual (C-in). uni: 4 loads; else gather ----
  f32x4 acc2[4][4];
  if (uni) {
#pragma unroll
    for (int mt = 0; mt < 4; mt++)
#pragma unroll
      for (int ct = 0; ct < 4; ct++)
#pragma unroll
        for (int rg = 0; rg < 4; rg++)
          acc2[mt][ct][rg] = gseed[ct];
  } else {
#pragma unroll
    for (int mt = 0; mt < 4; mt++)
#pragma unroll
      for (int rg = 0; rg < 4; rg++) {
        int p = 64 * mh + 16 * mt + 4 * quad + rg;
        const float* gr = &G[((size_t)b * 256 + lds_ids[p]) * 128 + 64 * chh + lr];
#pragma unroll
        for (int ct = 0; ct < 4; ct++)
          acc2[mt][ct][rg] = gr[16 * ct];
      }
  }

  // ---- conv2: 128 pts x 128 ch, K=128; W2 frags direct from global ----
#pragma unroll
  for (int ks = 0; ks < 4; ks++) {
    int ko = ks * 32 + quad * 8;
    s8v af[4], bfr[4];
#pragma unroll
    for (int mt = 0; mt < 4; mt++)
      af[mt] = *(const s8v*)&smem[(64 * mh + 16 * mt + lr) * 136 + ko];
#pragma unroll
    for (int ct = 0; ct < 4; ct++)
      bfr[ct] = *(const s8v*)&w2bf[(size_t)(64 * chh + 16 * ct + lr) * 384 + ko];
#pragma unroll
    for (int mt = 0; mt < 4; mt++)
#pragma unroll
      for (int ct = 0; ct < 4; ct++)
        acc2[mt][ct] = __builtin_amdgcn_mfma_f32_16x16x32_bf16(af[mt], bfr[ct], acc2[mt][ct], 0, 0, 0);
  }
  __syncthreads();   // #2 (A reads done -> H2 may overlay)

  // ---- bn2 + relu -> H2 [128][136] ----
#pragma unroll
  for (int ct = 0; ct < 4; ct++) {
    int c = 64 * chh + 16 * ct + lr;
    float sc = sc2[c], sh = sh2[c];
#pragma unroll
    for (int mt = 0; mt < 4; mt++)
#pragma unroll
      for (int rg = 0; rg < 4; rg++) {
        int p = 64 * mh + 16 * mt + 4 * quad + rg;
        float z = acc2[mt][ct][rg] * sc + sh;
        smem[p * 136 + c] = f2bf(fmaxf(z, 0.f));
      }
  }
  __syncthreads();   // #3

  // ---- conv3: 128 pts x 64 ch, K=128; W3 frags direct from global ----
  f32x4 acc3[2][4];
#pragma unroll
  for (int i = 0; i < 2; i++)
#pragma unroll
    for (int j = 0; j < 4; j++) acc3[i][j] = (f32x4)(0.f);
#pragma unroll
  for (int ks = 0; ks < 4; ks++) {
    int ko = ks * 32 + quad * 8;
    s8v af2[2], bf3[4];
#pragma unroll
    for (int mt = 0; mt < 2; mt++)
      af2[mt] = *(const s8v*)&smem[(32 * w + 16 * mt + lr) * 136 + ko];
#pragma unroll
    for (int ct = 0; ct < 4; ct++)
      bf3[ct] = *(const s8v*)&w3bf[(size_t)(16 * ct + lr) * 128 + ko];
#pragma unroll
    for (int mt = 0; mt < 2; mt++)
#pragma unroll
      for (int ct = 0; ct < 4; ct++)
        acc3[mt][ct] = __builtin_amdgcn_mfma_f32_16x16x32_bf16(af2[mt], bf3[ct], acc3[mt][ct], 0, 0, 0);
  }
  __syncthreads();   // #4 (H2 reads done -> H3 may overlay)

  // ---- bn3 + relu -> H3 [128][72] ----
#pragma unroll
  for (int ct = 0; ct < 4; ct++) {
    int c = 16 * ct + lr;
    float sc = sc3[c], sh = sh3[c];
#pragma unroll
    for (int mt = 0; mt < 2; mt++)
#pragma unroll
      for (int rg = 0; rg < 4; rg++) {
        int p = 32 * w + 16 * mt + 4 * quad + rg;
        float z = acc3[mt][ct][rg] * sc + sh;
        smem[p * 72 + c] = f2bf(fmaxf(z, 0.f));
      }
  }
  __syncthreads();   // #5

  // ---- conv4 (fp32 scalar, NC=2): 256 threads, 128 pts x 2 ch ----
  {
    int c = t >> 7, p = t & 127;
    float s = b4[c];
#pragma unroll
    for (int j = 0; j < 8; j++) {
      s8v hv = *(const s8v*)&smem[p * 72 + j * 8];
#pragma unroll
      for (int e = 0; e < 8; e++)
        s += bf2f(hv[e]) * w4[c * 64 + j * 8 + e];
    }
    out[((size_t)b * NC_ + c) * N_ + n0 + p] = s;
  }
}

// ---------------------------------------------------------------------------
extern "C" void kernel_launch(void* const* d_in, const int* in_sizes, int n_in,
                              void* d_out, int out_size, void* d_ws, size_t ws_size,
                              hipStream_t stream) {
  const float* gl   = (const float*)d_in[0];
  const float* lo   = (const float*)d_in[1];
  const float* cen  = (const float*)d_in[2];
  const int*   npc  = (const int*)d_in[3];
  const float* fc1w = (const float*)d_in[4];
  const float* fc1b = (const float*)d_in[5];
  const float* fc2w = (const float*)d_in[6];
  const float* fc2b = (const float*)d_in[7];
  const float* ipw  = (const float*)d_in[8];
  const float* ipb  = (const float*)d_in[9];
  const float* opw  = (const float*)d_in[10];
  const float* opb  = (const float*)d_in[11];
  const float* w2   = (const float*)d_in[12];
  const float* b2   = (const float*)d_in[13];
  const float* g2   = (const float*)d_in[14];
  const float* be2  = (const float*)d_in[15];
  const float* mu2  = (const float*)d_in[16];
  const float* va2  = (const float*)d_in[17];
  const float* w3   = (const float*)d_in[18];
  const float* b3   = (const float*)d_in[19];
  const float* g3   = (const float*)d_in[20];
  const float* be3  = (const float*)d_in[21];
  const float* mu3  = (const float*)d_in[22];
  const float* va3  = (const float*)d_in[23];
  const float* w4   = (const float*)d_in[24];
  const float* b4   = (const float*)d_in[25];

  char* ws = (char*)d_ws;
  float* qkv  = (float*)(ws);                  // 3,145,728
  short* Xhi  = (short*)(ws + 3145728);        // 524,288
  short* Xlo  = (short*)(ws + 3670016);
  short* Chi  = (short*)(ws + 4194304);
  short* Clo  = (short*)(ws + 4718592);
  float* G    = (float*)(ws + 5242880);        // 524,288 (B,256,128) fp32
  short* iph  = (short*)(ws + 5767168);        // 393,216
  short* ipl  = (short*)(ws + 6160384);
  short* Mh   = (short*)(ws + 6553600);        // 65,536
  short* Ml   = (short*)(ws + 6684672);        // 65,536
  short* w2bf = (short*)(ws + 6815744);        // 98,304
  short* w3bf = (short*)(ws + 6914048);        // 16,384
  int*   ids  = (int*)  (ws + 6930432);        // 262,144
  float* sc2  = (float*)(ws + 7192576);
  float* sh2  = (float*)(ws + 7193088);
  float* sc3  = (float*)(ws + 7193600);
  float* sh3  = (float*)(ws + 7193856);
  float* g0v  = (float*)(ws + 7194112);        // 512
  float* out  = (float*)d_out;

  prep_k<<<2177, 256, 0, stream>>>(npc, ids, ipw, opw, opb, w2, w3,
                                   b2, g2, be2, mu2, va2,
                                   b3, g3, be3, mu3, va3,
                                   iph, ipl, Mh, Ml, g0v, w2bf, w3bf,
                                   sc2, sh2, sc3, sh3,
                                   gl, cen, fc1w, fc1b, fc2w, fc2b, Xhi, Xlo);
  gemm_x3_k<<<dim3(16, 12), 256, 0, stream>>>(Xhi, Xlo, iph, ipl, ipb,
                                              qkv, B_ * S_, 768, E_);
  attn_k<<<B_ * H_ * 8, 256, 0, stream>>>(qkv, Chi, Clo);
  gk_k<<<dim3(16, 4), 256, 0, stream>>>(Chi, Clo, Mh, Ml, g0v, G);
  conv_fused_k<<<B_ * (N_ / 128), 256, 0, stream>>>(
      lo, G, ids, w2bf, w3bf, sc2, sh2, sc3, sh3, w4, b4, out);
}

// Round 7
// 310.470 us; speedup vs baseline: 1.0564x; 1.0020x over previous
//
#include <hip/hip_runtime.h>

#define B_   4
#define S_   256
#define E_   256
#define H_   8
#define LD_  128
#define N_   65536
#define NC_  2

typedef __attribute__((ext_vector_type(8))) short s8v;   // 8 bf16
typedef __attribute__((ext_vector_type(4))) float f32x4;

// RNE f32->bf16 via v_cvt_pk_bf16_f32 (identical rounding to integer RNE emu)
__device__ __forceinline__ short f2bf(float f) {
  unsigned u;
  asm("v_cvt_pk_bf16_f32 %0, %1, %2" : "=v"(u) : "v"(f), "v"(f));
  return (short)u;
}
__device__ __forceinline__ float bf2f(short s) {
  union { float f; unsigned u; } v; v.u = ((unsigned)(unsigned short)s) << 16;
  return v.f;
}
__device__ __forceinline__ s8v pack8(float4 a, float4 b) {
  union { s8v s; unsigned u[4]; } r;
  asm("v_cvt_pk_bf16_f32 %0, %1, %2" : "=v"(r.u[0]) : "v"(a.x), "v"(a.y));
  asm("v_cvt_pk_bf16_f32 %0, %1, %2" : "=v"(r.u[1]) : "v"(a.z), "v"(a.w));
  asm("v_cvt_pk_bf16_f32 %0, %1, %2" : "=v"(r.u[2]) : "v"(b.x), "v"(b.y));
  asm("v_cvt_pk_bf16_f32 %0, %1, %2" : "=v"(r.u[3]) : "v"(b.z), "v"(b.w));
  return r.s;
}

// ---------------------------------------------------------------------------
// prep_k: block-roles:
//   bid <  768          : weight convert / split + bn fold (ipw, w2, w3)
//   768 <= bid <= 1024  : ids fill
//   1025 <= bid <= 2048 : pos-MLP + gl^T add -> Xhi/Xlo
//   bid >= 2049         : M = W2b @ opw (fp32) -> Mh/Ml split; g0 = W2b @ opb
// ---------------------------------------------------------------------------
__global__ __launch_bounds__(256) void prep_k(
    const int* __restrict__ npc, int* __restrict__ ids,
    const float* __restrict__ ipw, const float* __restrict__ opw,
    const float* __restrict__ opb,
    const float* __restrict__ w2, const float* __restrict__ w3,
    const float* __restrict__ b2, const float* __restrict__ g2,
    const float* __restrict__ be2, const float* __restrict__ mu2,
    const float* __restrict__ va2,
    const float* __restrict__ b3, const float* __restrict__ g3,
    const float* __restrict__ be3, const float* __restrict__ mu3,
    const float* __restrict__ va3,
    short* __restrict__ iph, short* __restrict__ ipl,
    short* __restrict__ Mh, short* __restrict__ Ml,
    float* __restrict__ g0v,
    short* __restrict__ w2bf, short* __restrict__ w3bf,
    float* __restrict__ sc2, float* __restrict__ sh2,
    float* __restrict__ sc3, float* __restrict__ sh3,
    const float* __restrict__ gl, const float* __restrict__ cen,
    const float* __restrict__ fc1w, const float* __restrict__ fc1b,
    const float* __restrict__ fc2w, const float* __restrict__ fc2b,
    short* __restrict__ Xhi, short* __restrict__ Xlo) {
  __shared__ int red[256];
  __shared__ float hsh[16];
  __shared__ float wrow[256];
  __shared__ float gred[256];
  int bid = blockIdx.x, t = threadIdx.x;
  if (bid < 768) {
    int i = bid * 256 + t;
    if (i < 196608) {
      float v = ipw[i]; short h = f2bf(v);
      iph[i] = h; ipl[i] = f2bf(v - bf2f(h));
    }
    if (i < 49152) w2bf[i] = f2bf(w2[i]);
    if (i < 8192)  w3bf[i] = f2bf(w3[i]);
    if (i < 128) {
      float sc = g2[i] * rsqrtf(va2[i] + 1e-5f);
      sc2[i] = sc; sh2[i] = (b2[i] - mu2[i]) * sc + be2[i];
    }
    if (i < 64) {
      float sc = g3[i] * rsqrtf(va3[i] + 1e-5f);
      sc3[i] = sc; sh3[i] = (b3[i] - mu3[i]) * sc + be3[i];
    }
  } else if (bid <= 1024) {
    int s = bid - 768;   // 0..256
    int val = (s == 256) ? npc[t] : ((t < s) ? npc[t] : 0);
    red[t] = val;
    __syncthreads();
    for (int off = 128; off > 0; off >>= 1) {
      if (t < off) red[t] += red[t + off];
      __syncthreads();
    }
    int st = red[0];
    if (s < 256) {
      int en = st + npc[s]; if (en > N_) en = N_;
      for (int n = st + t; n < en; n += 256) ids[n] = s;
    } else {
      for (int n = st + t; n < N_; n += 256) ids[n] = 255;
    }
  } else if (bid <= 2048) {
    int bs = bid - 1025;   // 0..1023
    int b = bs >> 8, s = bs & 255;
    if (t < 16) {
      float c0 = cen[bs * 2 + 0], c1 = cen[bs * 2 + 1];
      float v = c0 * fc1w[2 * t] + c1 * fc1w[2 * t + 1] + fc1b[t];
      hsh[t] = (v >= 0.f) ? v : 0.01f * v;
    }
    __syncthreads();
    float p = fc2b[t];
#pragma unroll
    for (int j = 0; j < 16; j++) p += hsh[j] * fc2w[t * 16 + j];
    float v = gl[((size_t)s * B_ + b) * E_ + t] + p;
    short h = f2bf(v);
    Xhi[(size_t)bs * E_ + t] = h;
    Xlo[(size_t)bs * E_ + t] = f2bf(v - bf2f(h));
  } else {
    // M[c][e] = sum_k W2b[c][k] * opw[k][e];  W2b[c][k] = w2[c*384 + 128 + k]
    int c = bid - 2049;   // 0..127
    wrow[t] = w2[c * 384 + 128 + t];
    gred[t] = 0.f;
    __syncthreads();
    float acc = 0.f;
#pragma unroll 8
    for (int k = 0; k < 256; k++) acc += wrow[k] * opw[(size_t)k * 256 + t];
    short h = f2bf(acc);
    Mh[(size_t)c * 256 + t] = h;
    Ml[(size_t)c * 256 + t] = f2bf(acc - bf2f(h));
    // g0[c] = sum_k W2b[c][k] * opb[k]  (tree reduce, deterministic)
    gred[t] = wrow[t] * opb[t];
    __syncthreads();
    for (int off = 128; off > 0; off >>= 1) {
      if (t < off) gred[t] += gred[t + off];
      __syncthreads();
    }
    if (t == 0) g0v[c] = gred[0];
  }
}

// ---------------------------------------------------------------------------
// bf16x3 MFMA GEMM (qkv): C = (Ah+Al)(Wh+Wl)^T + bias -> fp32. 64x64 tiles.
// ---------------------------------------------------------------------------
__global__ __launch_bounds__(256) void gemm_x3_k(
    const short* __restrict__ Ah, const short* __restrict__ Al,
    const short* __restrict__ Wh, const short* __restrict__ Wl,
    const float* __restrict__ bias, float* __restrict__ Cf,
    int M, int N, int K) {
  __shared__ __align__(16) short gs[18432];
  const int AH = 0, AL = 4608, WH = 9216, WL = 13824;
  int t = threadIdx.x;
  int row0 = blockIdx.x * 64, col0 = blockIdx.y * 64;
  int w = t >> 6, l = t & 63, quad = l >> 4, lr = l & 15;
  int m0 = w * 16;
  int ar = t >> 2, aq = (t & 3) * 16;
  f32x4 acc[4];
#pragma unroll
  for (int i = 0; i < 4; i++) acc[i] = (f32x4)(0.f);

  for (int kc = 0; kc < K; kc += 64) {
    __syncthreads();
    {
      size_t ra = (size_t)(row0 + ar) * K + kc + aq;
      size_t rw = (size_t)(col0 + ar) * K + kc + aq;
      *(s8v*)&gs[AH + ar * 72 + aq]     = *(const s8v*)&Ah[ra];
      *(s8v*)&gs[AH + ar * 72 + aq + 8] = *(const s8v*)&Ah[ra + 8];
      *(s8v*)&gs[AL + ar * 72 + aq]     = *(const s8v*)&Al[ra];
      *(s8v*)&gs[AL + ar * 72 + aq + 8] = *(const s8v*)&Al[ra + 8];
      *(s8v*)&gs[WH + ar * 72 + aq]     = *(const s8v*)&Wh[rw];
      *(s8v*)&gs[WH + ar * 72 + aq + 8] = *(const s8v*)&Wh[rw + 8];
      *(s8v*)&gs[WL + ar * 72 + aq]     = *(const s8v*)&Wl[rw];
      *(s8v*)&gs[WL + ar * 72 + aq + 8] = *(const s8v*)&Wl[rw + 8];
    }
    __syncthreads();
#pragma unroll
    for (int ks = 0; ks < 2; ks++) {
      int ko = ks * 32 + quad * 8;
      s8v ah = *(const s8v*)&gs[AH + (m0 + lr) * 72 + ko];
      s8v al = *(const s8v*)&gs[AL + (m0 + lr) * 72 + ko];
#pragma unroll
      for (int ct = 0; ct < 4; ct++) {
        s8v bh = *(const s8v*)&gs[WH + (ct * 16 + lr) * 72 + ko];
        s8v bl = *(const s8v*)&gs[WL + (ct * 16 + lr) * 72 + ko];
        acc[ct] = __builtin_amdgcn_mfma_f32_16x16x32_bf16(ah, bh, acc[ct], 0, 0, 0);
        acc[ct] = __builtin_amdgcn_mfma_f32_16x16x32_bf16(al, bh, acc[ct], 0, 0, 0);
        acc[ct] = __builtin_amdgcn_mfma_f32_16x16x32_bf16(ah, bl, acc[ct], 0, 0, 0);
      }
    }
  }
#pragma unroll
  for (int ct = 0; ct < 4; ct++) {
    int c = col0 + ct * 16 + lr;
    float bb = bias[c];
#pragma unroll
    for (int rg = 0; rg < 4; rg++) {
      int r = row0 + m0 + quad * 4 + rg;
      Cf[(size_t)r * N + c] = acc[ct][rg] + bb;
    }
  }
}

// ---------------------------------------------------------------------------
// gk_k: G[1024][128] = (Chi+Clo) @ (Mh+Ml)^T + g0  (bf16x3, fp32 out).
// 64x32 tiles, grid (16,4).
// ---------------------------------------------------------------------------
__global__ __launch_bounds__(256) void gk_k(
    const short* __restrict__ Ah, const short* __restrict__ Al,
    const short* __restrict__ Wh, const short* __restrict__ Wl,
    const float* __restrict__ g0v, float* __restrict__ G) {
  __shared__ __align__(16) short gs[13824];
  const int AH = 0, AL = 4608, WH = 9216, WL = 11520;
  int t = threadIdx.x;
  int row0 = blockIdx.x * 64, col0 = blockIdx.y * 32;
  int w = t >> 6, l = t & 63, quad = l >> 4, lr = l & 15;
  int m0 = w * 16;
  int ar = t >> 2, aq = (t & 3) * 16;
  int wr = t >> 3, wq = (t & 7) * 8;
  f32x4 acc[2];
#pragma unroll
  for (int i = 0; i < 2; i++) acc[i] = (f32x4)(0.f);

  for (int kc = 0; kc < 256; kc += 64) {
    __syncthreads();
    {
      size_t ra = (size_t)(row0 + ar) * 256 + kc + aq;
      size_t rw = (size_t)(col0 + wr) * 256 + kc + wq;
      *(s8v*)&gs[AH + ar * 72 + aq]     = *(const s8v*)&Ah[ra];
      *(s8v*)&gs[AH + ar * 72 + aq + 8] = *(const s8v*)&Ah[ra + 8];
      *(s8v*)&gs[AL + ar * 72 + aq]     = *(const s8v*)&Al[ra];
      *(s8v*)&gs[AL + ar * 72 + aq + 8] = *(const s8v*)&Al[ra + 8];
      *(s8v*)&gs[WH + wr * 72 + wq]     = *(const s8v*)&Wh[rw];
      *(s8v*)&gs[WL + wr * 72 + wq]     = *(const s8v*)&Wl[rw];
    }
    __syncthreads();
#pragma unroll
    for (int ks = 0; ks < 2; ks++) {
      int ko = ks * 32 + quad * 8;
      s8v ah = *(const s8v*)&gs[AH + (m0 + lr) * 72 + ko];
      s8v al = *(const s8v*)&gs[AL + (m0 + lr) * 72 + ko];
#pragma unroll
      for (int ct = 0; ct < 2; ct++) {
        s8v bh = *(const s8v*)&gs[WH + (ct * 16 + lr) * 72 + ko];
        s8v bl = *(const s8v*)&gs[WL + (ct * 16 + lr) * 72 + ko];
        acc[ct] = __builtin_amdgcn_mfma_f32_16x16x32_bf16(ah, bh, acc[ct], 0, 0, 0);
        acc[ct] = __builtin_amdgcn_mfma_f32_16x16x32_bf16(al, bh, acc[ct], 0, 0, 0);
        acc[ct] = __builtin_amdgcn_mfma_f32_16x16x32_bf16(ah, bl, acc[ct], 0, 0, 0);
      }
    }
  }
#pragma unroll
  for (int ct = 0; ct < 2; ct++) {
    int c = col0 + ct * 16 + lr;
    float bb = g0v[c];
#pragma unroll
    for (int rg = 0; rg < 4; rg++) {
      int r = row0 + m0 + quad * 4 + rg;
      G[(size_t)r * 128 + c] = acc[ct][rg] + bb;
    }
  }
}

// ---------------------------------------------------------------------------
// attention (unchanged)
// ---------------------------------------------------------------------------
__global__ __launch_bounds__(256) void attn_k(const float* __restrict__ qkv,
                                              short* __restrict__ Chi,
                                              short* __restrict__ Clo) {
  int bid = blockIdx.x;
  int qt = bid & 7, h = (bid >> 3) & 7, b = bid >> 6;
  __shared__ __align__(16) float smem[16384];
  float* Kx = smem;
  float* Vx = smem + 8192;
  int t = threadIdx.x;
#pragma unroll
  for (int i = 0; i < 8; i++) {
    int row = i * 32 + (t >> 3);
    int d4 = (t & 7) * 4;
    const float* base = qkv + (size_t)(b * S_ + row) * 768 + h * 32 + d4;
    *(float4*)&Kx[row * 32 + d4] = *(const float4*)(base + 256);
    *(float4*)&Vx[row * 32 + d4] = *(const float4*)(base + 512);
  }
  int r = t & 31, g = t >> 5;
  float q[32];
  {
    const float* qb = qkv + (size_t)(b * S_ + qt * 32 + r) * 768 + h * 32;
#pragma unroll
    for (int d4 = 0; d4 < 32; d4 += 4) {
      float4 v = *(const float4*)(qb + d4);
      q[d4] = v.x; q[d4 + 1] = v.y; q[d4 + 2] = v.z; q[d4 + 3] = v.w;
    }
  }
  __syncthreads();
  const float scale = 0.17677669529663687f;
  int kk0 = g * 32;
  float sc[32];
  float m = -1e30f;
#pragma unroll
  for (int kk = 0; kk < 32; kk++) {
    const float* kr = &Kx[(kk0 + kk) * 32];
    float4 a = (float4){0.f, 0.f, 0.f, 0.f};
#pragma unroll
    for (int d4 = 0; d4 < 32; d4 += 4) {
      float4 kv = *(const float4*)(kr + d4);
      a.x += q[d4] * kv.x; a.y += q[d4 + 1] * kv.y;
      a.z += q[d4 + 2] * kv.z; a.w += q[d4 + 3] * kv.w;
    }
    float s = ((a.x + a.y) + (a.z + a.w)) * scale;
    sc[kk] = s;
    m = fmaxf(m, s);
  }
  float lsum = 0.f;
  float ctx[32];
#pragma unroll
  for (int d = 0; d < 32; d++) ctx[d] = 0.f;
#pragma unroll
  for (int kk = 0; kk < 32; kk++) {
    const float* vr = &Vx[(kk0 + kk) * 32];
    float p = __expf(sc[kk] - m);
    lsum += p;
#pragma unroll
    for (int d4 = 0; d4 < 32; d4 += 4) {
      float4 vv = *(const float4*)(vr + d4);
      ctx[d4] += p * vv.x; ctx[d4 + 1] += p * vv.y;
      ctx[d4 + 2] += p * vv.z; ctx[d4 + 3] += p * vv.w;
    }
  }
  __syncthreads();
  float* ctxbuf = smem;
  float* mbuf = smem + 8192;
  float* lbuf = smem + 8448;
  mbuf[g * 32 + r] = m;
  lbuf[g * 32 + r] = lsum;
#pragma unroll
  for (int d = 0; d < 32; d++)
    ctxbuf[(g * 32 + r) * 32 + ((d + r) & 31)] = ctx[d];
  __syncthreads();
  int r2 = t & 31, dq = t >> 5;
  float M = -1e30f;
#pragma unroll
  for (int gg = 0; gg < 8; gg++) M = fmaxf(M, mbuf[gg * 32 + r2]);
  float wg[8]; float L = 0.f;
#pragma unroll
  for (int gg = 0; gg < 8; gg++) {
    wg[gg] = __expf(mbuf[gg * 32 + r2] - M);
    L += lbuf[gg * 32 + r2] * wg[gg];
  }
  float invL = 1.f / L;
  size_t base = (size_t)(b * S_ + qt * 32 + r2) * E_ + h * 32;
#pragma unroll
  for (int dd = 0; dd < 4; dd++) {
    int d = dq * 4 + dd;
    float o = 0.f;
#pragma unroll
    for (int gg = 0; gg < 8; gg++)
      o += ctxbuf[(gg * 32 + r2) * 32 + ((d + r2) & 31)] * wg[gg];
    o *= invL;
    short hi = f2bf(o);
    Chi[base + d] = hi;
    Clo[base + d] = f2bf(o - bf2f(hi));
  }
}

// ---------------------------------------------------------------------------
// conv_fused v7 = v6 (measured 79.5us) with bn3+conv4 fused IN-REGISTER:
//   - after conv3, thread holds channels {16ct+lr} of 8 points; bn3+relu in
//     regs, partial dot vs w4 (both out channels), 16-lane __shfl_xor
//     butterfly (masks 1,2,4,8 stay inside the quad group), each lane stores
//     one (point,c4) selected by compile-time-unrolled compares (no runtime
//     array indexing -> no scratch).
//   - removes barriers #4/#5, the H3 LDS overlay, and H3's bf16 rounding
//     (conv4 consumes fp32 -> closer to reference). Barriers 5 -> 3.
// ---------------------------------------------------------------------------
__global__ __launch_bounds__(256, 4) void conv_fused_k(
    const float* __restrict__ lo, const float* __restrict__ G,
    const int* __restrict__ ids,
    const short* __restrict__ w2bf, const short* __restrict__ w3bf,
    const float* __restrict__ sc2, const float* __restrict__ sh2,
    const float* __restrict__ sc3, const float* __restrict__ sh3,
    const float* __restrict__ w4, const float* __restrict__ b4,
    float* __restrict__ out) {
  __shared__ __align__(16) short smem[17408];   // 34816 B (A tile, H2 overlay)
  __shared__ int lds_ids[128];
  int t = threadIdx.x;
  int bid = blockIdx.x;
  int b = bid >> 9;
  int n0 = (bid & 511) << 7;
  int w = t >> 6, l = t & 63;
  int quad = l >> 4, lr = l & 15;
  int mh = w & 1, chh = w >> 1;
  int ar = t >> 1, akh = (t & 1) * 64;
  const float* lob = &lo[((size_t)b * N_ + n0 + ar) * LD_ + akh];

  // ---- G fast-path loads (issued first; latency hides under staging) ----
  int id0 = ids[n0], id127 = ids[n0 + 127];
  bool uni = (id0 == id127);
  float gseed[4];
  {
    const float* gr = &G[((size_t)b * 256 + id0) * 128 + 64 * chh + lr];
#pragma unroll
    for (int ct = 0; ct < 4; ct++) gseed[ct] = gr[16 * ct];
  }
  if (t < 128) lds_ids[t] = ids[n0 + t];

  // ---- stage A full-K (64 floats/thread, two 32-float chunks) ----
  {
    float4 pf[8];
#pragma unroll
    for (int j = 0; j < 8; j++) pf[j] = *(const float4*)(lob + j * 4);
#pragma unroll
    for (int j = 0; j < 4; j++)
      *(s8v*)&smem[ar * 136 + akh + j * 8] = pack8(pf[2 * j], pf[2 * j + 1]);
#pragma unroll
    for (int j = 0; j < 8; j++) pf[j] = *(const float4*)(lob + 32 + j * 4);
#pragma unroll
    for (int j = 0; j < 4; j++)
      *(s8v*)&smem[ar * 136 + akh + 32 + j * 8] = pack8(pf[2 * j], pf[2 * j + 1]);
  }
  __syncthreads();   // #1

  // ---- seed acc2 with G residual (C-in). uni: 4 loads; else gather ----
  f32x4 acc2[4][4];
  if (uni) {
#pragma unroll
    for (int mt = 0; mt < 4; mt++)
#pragma unroll
      for (int ct = 0; ct < 4; ct++)
#pragma unroll
        for (int rg = 0; rg < 4; rg++)
          acc2[mt][ct][rg] = gseed[ct];
  } else {
#pragma unroll
    for (int mt = 0; mt < 4; mt++)
#pragma unroll
      for (int rg = 0; rg < 4; rg++) {
        int p = 64 * mh + 16 * mt + 4 * quad + rg;
        const float* gr = &G[((size_t)b * 256 + lds_ids[p]) * 128 + 64 * chh + lr];
#pragma unroll
        for (int ct = 0; ct < 4; ct++)
          acc2[mt][ct][rg] = gr[16 * ct];
      }
  }

  // ---- conv2: 128 pts x 128 ch, K=128; W2 frags direct from global ----
#pragma unroll
  for (int ks = 0; ks < 4; ks++) {
    int ko = ks * 32 + quad * 8;
    s8v af[4], bfr[4];
#pragma unroll
    for (int mt = 0; mt < 4; mt++)
      af[mt] = *(const s8v*)&smem[(64 * mh + 16 * mt + lr) * 136 + ko];
#pragma unroll
    for (int ct = 0; ct < 4; ct++)
      bfr[ct] = *(const s8v*)&w2bf[(size_t)(64 * chh + 16 * ct + lr) * 384 + ko];
#pragma unroll
    for (int mt = 0; mt < 4; mt++)
#pragma unroll
      for (int ct = 0; ct < 4; ct++)
        acc2[mt][ct] = __builtin_amdgcn_mfma_f32_16x16x32_bf16(af[mt], bfr[ct], acc2[mt][ct], 0, 0, 0);
  }
  __syncthreads();   // #2 (A reads done -> H2 may overlay)

  // ---- bn2 + relu -> H2 [128][136] ----
#pragma unroll
  for (int ct = 0; ct < 4; ct++) {
    int c = 64 * chh + 16 * ct + lr;
    float sc = sc2[c], sh = sh2[c];
#pragma unroll
    for (int mt = 0; mt < 4; mt++)
#pragma unroll
      for (int rg = 0; rg < 4; rg++) {
        int p = 64 * mh + 16 * mt + 4 * quad + rg;
        float z = acc2[mt][ct][rg] * sc + sh;
        smem[p * 136 + c] = f2bf(fmaxf(z, 0.f));
      }
  }
  __syncthreads();   // #3

  // ---- conv3: 128 pts x 64 ch, K=128; W3 frags direct from global ----
  f32x4 acc3[2][4];
#pragma unroll
  for (int i = 0; i < 2; i++)
#pragma unroll
    for (int j = 0; j < 4; j++) acc3[i][j] = (f32x4)(0.f);
#pragma unroll
  for (int ks = 0; ks < 4; ks++) {
    int ko = ks * 32 + quad * 8;
    s8v af2[2], bf3[4];
#pragma unroll
    for (int mt = 0; mt < 2; mt++)
      af2[mt] = *(const s8v*)&smem[(32 * w + 16 * mt + lr) * 136 + ko];
#pragma unroll
    for (int ct = 0; ct < 4; ct++)
      bf3[ct] = *(const s8v*)&w3bf[(size_t)(16 * ct + lr) * 128 + ko];
#pragma unroll
    for (int mt = 0; mt < 2; mt++)
#pragma unroll
      for (int ct = 0; ct < 4; ct++)
        acc3[mt][ct] = __builtin_amdgcn_mfma_f32_16x16x32_bf16(af2[mt], bf3[ct], acc3[mt][ct], 0, 0, 0);
  }

  // ---- bn3 + relu + conv4, fully in-register (no barriers) ----
  // thread (w, quad, lr) holds channels {16ct+lr} of points 32w+16mt+4quad+rg
  float w4c0[4], w4c1[4], s3[4], b3sh[4];
#pragma unroll
  for (int ct = 0; ct < 4; ct++) {
    int c = 16 * ct + lr;
    s3[ct] = sc3[c]; b3sh[ct] = sh3[c];
    w4c0[ct] = w4[c];        // out-ch 0
    w4c1[ct] = w4[64 + c];   // out-ch 1
  }
  int c4s = lr & 1, rgs = (lr >> 1) & 3, mts = lr >> 3;   // this lane's output
  float myout = 0.f;
#pragma unroll
  for (int mt = 0; mt < 2; mt++)
#pragma unroll
    for (int rg = 0; rg < 4; rg++) {
      float p0 = 0.f, p1 = 0.f;
#pragma unroll
      for (int ct = 0; ct < 4; ct++) {
        float z = fmaxf(fmaf(acc3[mt][ct][rg], s3[ct], b3sh[ct]), 0.f);
        p0 = fmaf(z, w4c0[ct], p0);
        p1 = fmaf(z, w4c1[ct], p1);
      }
#pragma unroll
      for (int m = 1; m < 16; m <<= 1) {
        p0 += __shfl_xor(p0, m, 64);
        p1 += __shfl_xor(p1, m, 64);
      }
      // compile-time (mt,rg) vs this lane's (mts,rgs): fold to cndmask
      bool mine = (mt == mts) && (rg == rgs);
      float pv = c4s ? p1 : p0;
      myout = mine ? pv : myout;
    }
  {
    int p = 32 * w + 16 * mts + 4 * quad + rgs;
    out[((size_t)b * NC_ + c4s) * N_ + n0 + p] = myout + b4[c4s];
  }
}

// ---------------------------------------------------------------------------
extern "C" void kernel_launch(void* const* d_in, const int* in_sizes, int n_in,
                              void* d_out, int out_size, void* d_ws, size_t ws_size,
                              hipStream_t stream) {
  const float* gl   = (const float*)d_in[0];
  const float* lo   = (const float*)d_in[1];
  const float* cen  = (const float*)d_in[2];
  const int*   npc  = (const int*)d_in[3];
  const float* fc1w = (const float*)d_in[4];
  const float* fc1b = (const float*)d_in[5];
  const float* fc2w = (const float*)d_in[6];
  const float* fc2b = (const float*)d_in[7];
  const float* ipw  = (const float*)d_in[8];
  const float* ipb  = (const float*)d_in[9];
  const float* opw  = (const float*)d_in[10];
  const float* opb  = (const float*)d_in[11];
  const float* w2   = (const float*)d_in[12];
  const float* b2   = (const float*)d_in[13];
  const float* g2   = (const float*)d_in[14];
  const float* be2  = (const float*)d_in[15];
  const float* mu2  = (const float*)d_in[16];
  const float* va2  = (const float*)d_in[17];
  const float* w3   = (const float*)d_in[18];
  const float* b3   = (const float*)d_in[19];
  const float* g3   = (const float*)d_in[20];
  const float* be3  = (const float*)d_in[21];
  const float* mu3  = (const float*)d_in[22];
  const float* va3  = (const float*)d_in[23];
  const float* w4   = (const float*)d_in[24];
  const float* b4   = (const float*)d_in[25];

  char* ws = (char*)d_ws;
  float* qkv  = (float*)(ws);                  // 3,145,728
  short* Xhi  = (short*)(ws + 3145728);        // 524,288
  short* Xlo  = (short*)(ws + 3670016);
  short* Chi  = (short*)(ws + 4194304);
  short* Clo  = (short*)(ws + 4718592);
  float* G    = (float*)(ws + 5242880);        // 524,288 (B,256,128) fp32
  short* iph  = (short*)(ws + 5767168);        // 393,216
  short* ipl  = (short*)(ws + 6160384);
  short* Mh   = (short*)(ws + 6553600);        // 65,536
  short* Ml   = (short*)(ws + 6684672);        // 65,536
  short* w2bf = (short*)(ws + 6815744);        // 98,304
  short* w3bf = (short*)(ws + 6914048);        // 16,384
  int*   ids  = (int*)  (ws + 6930432);        // 262,144
  float* sc2  = (float*)(ws + 7192576);
  float* sh2  = (float*)(ws + 7193088);
  float* sc3  = (float*)(ws + 7193600);
  float* sh3  = (float*)(ws + 7193856);
  float* g0v  = (float*)(ws + 7194112);        // 512
  float* out  = (float*)d_out;

  prep_k<<<2177, 256, 0, stream>>>(npc, ids, ipw, opw, opb, w2, w3,
                                   b2, g2, be2, mu2, va2,
                                   b3, g3, be3, mu3, va3,
                                   iph, ipl, Mh, Ml, g0v, w2bf, w3bf,
                                   sc2, sh2, sc3, sh3,
                                   gl, cen, fc1w, fc1b, fc2w, fc2b, Xhi, Xlo);
  gemm_x3_k<<<dim3(16, 12), 256, 0, stream>>>(Xhi, Xlo, iph, ipl, ipb,
                                              qkv, B_ * S_, 768, E_);
  attn_k<<<B_ * H_ * 8, 256, 0, stream>>>(qkv, Chi, Clo);
  gk_k<<<dim3(16, 4), 256, 0, stream>>>(Chi, Clo, Mh, Ml, g0v, G);
  conv_fused_k<<<B_ * (N_ / 128), 256, 0, stream>>>(
      lo, G, ids, w2bf, w3bf, sc2, sh2, sc3, sh3, w4, b4, out);
}

// Round 8
// 300.634 us; speedup vs baseline: 1.0909x; 1.0327x over previous
//
#include <hip/hip_runtime.h>

#define B_   4
#define S_   256
#define E_   256
#define H_   8
#define LD_  128
#define N_   65536
#define NC_  2

typedef __attribute__((ext_vector_type(8))) short s8v;   // 8 bf16
typedef __attribute__((ext_vector_type(4))) float f32x4;

// RNE f32->bf16 via v_cvt_pk_bf16_f32 (identical rounding to integer RNE emu)
__device__ __forceinline__ short f2bf(float f) {
  unsigned u;
  asm("v_cvt_pk_bf16_f32 %0, %1, %2" : "=v"(u) : "v"(f), "v"(f));
  return (short)u;
}
__device__ __forceinline__ float bf2f(short s) {
  union { float f; unsigned u; } v; v.u = ((unsigned)(unsigned short)s) << 16;
  return v.f;
}
__device__ __forceinline__ s8v pack8(float4 a, float4 b) {
  union { s8v s; unsigned u[4]; } r;
  asm("v_cvt_pk_bf16_f32 %0, %1, %2" : "=v"(r.u[0]) : "v"(a.x), "v"(a.y));
  asm("v_cvt_pk_bf16_f32 %0, %1, %2" : "=v"(r.u[1]) : "v"(a.z), "v"(a.w));
  asm("v_cvt_pk_bf16_f32 %0, %1, %2" : "=v"(r.u[2]) : "v"(b.x), "v"(b.y));
  asm("v_cvt_pk_bf16_f32 %0, %1, %2" : "=v"(r.u[3]) : "v"(b.z), "v"(b.w));
  return r.s;
}

// ---------------------------------------------------------------------------
// prep_k: block-roles:
//   bid <  768          : weight convert/split + bn fold + FRAGMENT-MAJOR
//                         repack of conv2/conv3 weights (w2p/w3p): each wave's
//                         MFMA B-fragment load becomes 64 lanes x 16B = 1 KB
//                         contiguous (was stride-768B, 25% line efficiency).
//   768 <= bid <= 1024  : ids fill
//   1025 <= bid <= 2048 : pos-MLP + gl^T add -> Xhi/Xlo
//   bid >= 2049         : M = W2b @ opw (fp32) -> Mh/Ml split; g0 = W2b @ opb
// ---------------------------------------------------------------------------
__global__ __launch_bounds__(256) void prep_k(
    const int* __restrict__ npc, int* __restrict__ ids,
    const float* __restrict__ ipw, const float* __restrict__ opw,
    const float* __restrict__ opb,
    const float* __restrict__ w2, const float* __restrict__ w3,
    const float* __restrict__ b2, const float* __restrict__ g2,
    const float* __restrict__ be2, const float* __restrict__ mu2,
    const float* __restrict__ va2,
    const float* __restrict__ b3, const float* __restrict__ g3,
    const float* __restrict__ be3, const float* __restrict__ mu3,
    const float* __restrict__ va3,
    short* __restrict__ iph, short* __restrict__ ipl,
    short* __restrict__ Mh, short* __restrict__ Ml,
    float* __restrict__ g0v,
    short* __restrict__ w2p, short* __restrict__ w3p,
    float* __restrict__ sc2, float* __restrict__ sh2,
    float* __restrict__ sc3, float* __restrict__ sh3,
    const float* __restrict__ gl, const float* __restrict__ cen,
    const float* __restrict__ fc1w, const float* __restrict__ fc1b,
    const float* __restrict__ fc2w, const float* __restrict__ fc2b,
    short* __restrict__ Xhi, short* __restrict__ Xlo) {
  __shared__ int red[256];
  __shared__ float hsh[16];
  __shared__ float wrow[256];
  __shared__ float gred[256];
  int bid = blockIdx.x, t = threadIdx.x;
  if (bid < 768) {
    int i = bid * 256 + t;
    if (i < 196608) {
      float v = ipw[i]; short h = f2bf(v);
      iph[i] = h; ipl[i] = f2bf(v - bf2f(h));
    }
    if (i < 16384) {   // w2p: conv2 weights, fragment-major
      int g = i >> 9, l2 = (i >> 3) & 63, j = i & 7;
      int chh = g >> 4, ct = (g >> 2) & 3, ks = g & 3;
      int row = 64 * chh + 16 * ct + (l2 & 15);
      int col = ks * 32 + (l2 >> 4) * 8 + j;
      w2p[i] = f2bf(w2[row * 384 + col]);
    }
    if (i < 8192) {    // w3p: conv3 weights, fragment-major
      int g = i >> 9, l2 = (i >> 3) & 63, j = i & 7;
      int ct = g >> 2, ks = g & 3;
      int row = 16 * ct + (l2 & 15);
      int col = ks * 32 + (l2 >> 4) * 8 + j;
      w3p[i] = f2bf(w3[row * 128 + col]);
    }
    if (i < 128) {
      float sc = g2[i] * rsqrtf(va2[i] + 1e-5f);
      sc2[i] = sc; sh2[i] = (b2[i] - mu2[i]) * sc + be2[i];
    }
    if (i < 64) {
      float sc = g3[i] * rsqrtf(va3[i] + 1e-5f);
      sc3[i] = sc; sh3[i] = (b3[i] - mu3[i]) * sc + be3[i];
    }
  } else if (bid <= 1024) {
    int s = bid - 768;   // 0..256
    int val = (s == 256) ? npc[t] : ((t < s) ? npc[t] : 0);
    red[t] = val;
    __syncthreads();
    for (int off = 128; off > 0; off >>= 1) {
      if (t < off) red[t] += red[t + off];
      __syncthreads();
    }
    int st = red[0];
    if (s < 256) {
      int en = st + npc[s]; if (en > N_) en = N_;
      for (int n = st + t; n < en; n += 256) ids[n] = s;
    } else {
      for (int n = st + t; n < N_; n += 256) ids[n] = 255;
    }
  } else if (bid <= 2048) {
    int bs = bid - 1025;   // 0..1023
    int b = bs >> 8, s = bs & 255;
    if (t < 16) {
      float c0 = cen[bs * 2 + 0], c1 = cen[bs * 2 + 1];
      float v = c0 * fc1w[2 * t] + c1 * fc1w[2 * t + 1] + fc1b[t];
      hsh[t] = (v >= 0.f) ? v : 0.01f * v;
    }
    __syncthreads();
    float p = fc2b[t];
#pragma unroll
    for (int j = 0; j < 16; j++) p += hsh[j] * fc2w[t * 16 + j];
    float v = gl[((size_t)s * B_ + b) * E_ + t] + p;
    short h = f2bf(v);
    Xhi[(size_t)bs * E_ + t] = h;
    Xlo[(size_t)bs * E_ + t] = f2bf(v - bf2f(h));
  } else {
    // M[c][e] = sum_k W2b[c][k] * opw[k][e];  W2b[c][k] = w2[c*384 + 128 + k]
    int c = bid - 2049;   // 0..127
    wrow[t] = w2[c * 384 + 128 + t];
    gred[t] = 0.f;
    __syncthreads();
    float acc = 0.f;
#pragma unroll 8
    for (int k = 0; k < 256; k++) acc += wrow[k] * opw[(size_t)k * 256 + t];
    short h = f2bf(acc);
    Mh[(size_t)c * 256 + t] = h;
    Ml[(size_t)c * 256 + t] = f2bf(acc - bf2f(h));
    // g0[c] = sum_k W2b[c][k] * opb[k]  (tree reduce, deterministic)
    gred[t] = wrow[t] * opb[t];
    __syncthreads();
    for (int off = 128; off > 0; off >>= 1) {
      if (t < off) gred[t] += gred[t + off];
      __syncthreads();
    }
    if (t == 0) g0v[c] = gred[0];
  }
}

// ---------------------------------------------------------------------------
// bf16x3 MFMA GEMM (qkv): C = (Ah+Al)(Wh+Wl)^T + bias -> fp32. 64x64 tiles.
// ---------------------------------------------------------------------------
__global__ __launch_bounds__(256) void gemm_x3_k(
    const short* __restrict__ Ah, const short* __restrict__ Al,
    const short* __restrict__ Wh, const short* __restrict__ Wl,
    const float* __restrict__ bias, float* __restrict__ Cf,
    int M, int N, int K) {
  __shared__ __align__(16) short gs[18432];
  const int AH = 0, AL = 4608, WH = 9216, WL = 13824;
  int t = threadIdx.x;
  int row0 = blockIdx.x * 64, col0 = blockIdx.y * 64;
  int w = t >> 6, l = t & 63, quad = l >> 4, lr = l & 15;
  int m0 = w * 16;
  int ar = t >> 2, aq = (t & 3) * 16;
  f32x4 acc[4];
#pragma unroll
  for (int i = 0; i < 4; i++) acc[i] = (f32x4)(0.f);

  for (int kc = 0; kc < K; kc += 64) {
    __syncthreads();
    {
      size_t ra = (size_t)(row0 + ar) * K + kc + aq;
      size_t rw = (size_t)(col0 + ar) * K + kc + aq;
      *(s8v*)&gs[AH + ar * 72 + aq]     = *(const s8v*)&Ah[ra];
      *(s8v*)&gs[AH + ar * 72 + aq + 8] = *(const s8v*)&Ah[ra + 8];
      *(s8v*)&gs[AL + ar * 72 + aq]     = *(const s8v*)&Al[ra];
      *(s8v*)&gs[AL + ar * 72 + aq + 8] = *(const s8v*)&Al[ra + 8];
      *(s8v*)&gs[WH + ar * 72 + aq]     = *(const s8v*)&Wh[rw];
      *(s8v*)&gs[WH + ar * 72 + aq + 8] = *(const s8v*)&Wh[rw + 8];
      *(s8v*)&gs[WL + ar * 72 + aq]     = *(const s8v*)&Wl[rw];
      *(s8v*)&gs[WL + ar * 72 + aq + 8] = *(const s8v*)&Wl[rw + 8];
    }
    __syncthreads();
#pragma unroll
    for (int ks = 0; ks < 2; ks++) {
      int ko = ks * 32 + quad * 8;
      s8v ah = *(const s8v*)&gs[AH + (m0 + lr) * 72 + ko];
      s8v al = *(const s8v*)&gs[AL + (m0 + lr) * 72 + ko];
#pragma unroll
      for (int ct = 0; ct < 4; ct++) {
        s8v bh = *(const s8v*)&gs[WH + (ct * 16 + lr) * 72 + ko];
        s8v bl = *(const s8v*)&gs[WL + (ct * 16 + lr) * 72 + ko];
        acc[ct] = __builtin_amdgcn_mfma_f32_16x16x32_bf16(ah, bh, acc[ct], 0, 0, 0);
        acc[ct] = __builtin_amdgcn_mfma_f32_16x16x32_bf16(al, bh, acc[ct], 0, 0, 0);
        acc[ct] = __builtin_amdgcn_mfma_f32_16x16x32_bf16(ah, bl, acc[ct], 0, 0, 0);
      }
    }
  }
#pragma unroll
  for (int ct = 0; ct < 4; ct++) {
    int c = col0 + ct * 16 + lr;
    float bb = bias[c];
#pragma unroll
    for (int rg = 0; rg < 4; rg++) {
      int r = row0 + m0 + quad * 4 + rg;
      Cf[(size_t)r * N + c] = acc[ct][rg] + bb;
    }
  }
}

// ---------------------------------------------------------------------------
// gk_k: G[1024][128] = (Chi+Clo) @ (Mh+Ml)^T + g0  (bf16x3, fp32 out).
// 64x32 tiles, grid (16,4).
// ---------------------------------------------------------------------------
__global__ __launch_bounds__(256) void gk_k(
    const short* __restrict__ Ah, const short* __restrict__ Al,
    const short* __restrict__ Wh, const short* __restrict__ Wl,
    const float* __restrict__ g0v, float* __restrict__ G) {
  __shared__ __align__(16) short gs[13824];
  const int AH = 0, AL = 4608, WH = 9216, WL = 11520;
  int t = threadIdx.x;
  int row0 = blockIdx.x * 64, col0 = blockIdx.y * 32;
  int w = t >> 6, l = t & 63, quad = l >> 4, lr = l & 15;
  int m0 = w * 16;
  int ar = t >> 2, aq = (t & 3) * 16;
  int wr = t >> 3, wq = (t & 7) * 8;
  f32x4 acc[2];
#pragma unroll
  for (int i = 0; i < 2; i++) acc[i] = (f32x4)(0.f);

  for (int kc = 0; kc < 256; kc += 64) {
    __syncthreads();
    {
      size_t ra = (size_t)(row0 + ar) * 256 + kc + aq;
      size_t rw = (size_t)(col0 + wr) * 256 + kc + wq;
      *(s8v*)&gs[AH + ar * 72 + aq]     = *(const s8v*)&Ah[ra];
      *(s8v*)&gs[AH + ar * 72 + aq + 8] = *(const s8v*)&Ah[ra + 8];
      *(s8v*)&gs[AL + ar * 72 + aq]     = *(const s8v*)&Al[ra];
      *(s8v*)&gs[AL + ar * 72 + aq + 8] = *(const s8v*)&Al[ra + 8];
      *(s8v*)&gs[WH + wr * 72 + wq]     = *(const s8v*)&Wh[rw];
      *(s8v*)&gs[WL + wr * 72 + wq]     = *(const s8v*)&Wl[rw];
    }
    __syncthreads();
#pragma unroll
    for (int ks = 0; ks < 2; ks++) {
      int ko = ks * 32 + quad * 8;
      s8v ah = *(const s8v*)&gs[AH + (m0 + lr) * 72 + ko];
      s8v al = *(const s8v*)&gs[AL + (m0 + lr) * 72 + ko];
#pragma unroll
      for (int ct = 0; ct < 2; ct++) {
        s8v bh = *(const s8v*)&gs[WH + (ct * 16 + lr) * 72 + ko];
        s8v bl = *(const s8v*)&gs[WL + (ct * 16 + lr) * 72 + ko];
        acc[ct] = __builtin_amdgcn_mfma_f32_16x16x32_bf16(ah, bh, acc[ct], 0, 0, 0);
        acc[ct] = __builtin_amdgcn_mfma_f32_16x16x32_bf16(al, bh, acc[ct], 0, 0, 0);
        acc[ct] = __builtin_amdgcn_mfma_f32_16x16x32_bf16(ah, bl, acc[ct], 0, 0, 0);
      }
    }
  }
#pragma unroll
  for (int ct = 0; ct < 2; ct++) {
    int c = col0 + ct * 16 + lr;
    float bb = g0v[c];
#pragma unroll
    for (int rg = 0; rg < 4; rg++) {
      int r = row0 + m0 + quad * 4 + rg;
      G[(size_t)r * 128 + c] = acc[ct][rg] + bb;
    }
  }
}

// ---------------------------------------------------------------------------
// attention (unchanged)
// ---------------------------------------------------------------------------
__global__ __launch_bounds__(256) void attn_k(const float* __restrict__ qkv,
                                              short* __restrict__ Chi,
                                              short* __restrict__ Clo) {
  int bid = blockIdx.x;
  int qt = bid & 7, h = (bid >> 3) & 7, b = bid >> 6;
  __shared__ __align__(16) float smem[16384];
  float* Kx = smem;
  float* Vx = smem + 8192;
  int t = threadIdx.x;
#pragma unroll
  for (int i = 0; i < 8; i++) {
    int row = i * 32 + (t >> 3);
    int d4 = (t & 7) * 4;
    const float* base = qkv + (size_t)(b * S_ + row) * 768 + h * 32 + d4;
    *(float4*)&Kx[row * 32 + d4] = *(const float4*)(base + 256);
    *(float4*)&Vx[row * 32 + d4] = *(const float4*)(base + 512);
  }
  int r = t & 31, g = t >> 5;
  float q[32];
  {
    const float* qb = qkv + (size_t)(b * S_ + qt * 32 + r) * 768 + h * 32;
#pragma unroll
    for (int d4 = 0; d4 < 32; d4 += 4) {
      float4 v = *(const float4*)(qb + d4);
      q[d4] = v.x; q[d4 + 1] = v.y; q[d4 + 2] = v.z; q[d4 + 3] = v.w;
    }
  }
  __syncthreads();
  const float scale = 0.17677669529663687f;
  int kk0 = g * 32;
  float sc[32];
  float m = -1e30f;
#pragma unroll
  for (int kk = 0; kk < 32; kk++) {
    const float* kr = &Kx[(kk0 + kk) * 32];
    float4 a = (float4){0.f, 0.f, 0.f, 0.f};
#pragma unroll
    for (int d4 = 0; d4 < 32; d4 += 4) {
      float4 kv = *(const float4*)(kr + d4);
      a.x += q[d4] * kv.x; a.y += q[d4 + 1] * kv.y;
      a.z += q[d4 + 2] * kv.z; a.w += q[d4 + 3] * kv.w;
    }
    float s = ((a.x + a.y) + (a.z + a.w)) * scale;
    sc[kk] = s;
    m = fmaxf(m, s);
  }
  float lsum = 0.f;
  float ctx[32];
#pragma unroll
  for (int d = 0; d < 32; d++) ctx[d] = 0.f;
#pragma unroll
  for (int kk = 0; kk < 32; kk++) {
    const float* vr = &Vx[(kk0 + kk) * 32];
    float p = __expf(sc[kk] - m);
    lsum += p;
#pragma unroll
    for (int d4 = 0; d4 < 32; d4 += 4) {
      float4 vv = *(const float4*)(vr + d4);
      ctx[d4] += p * vv.x; ctx[d4 + 1] += p * vv.y;
      ctx[d4 + 2] += p * vv.z; ctx[d4 + 3] += p * vv.w;
    }
  }
  __syncthreads();
  float* ctxbuf = smem;
  float* mbuf = smem + 8192;
  float* lbuf = smem + 8448;
  mbuf[g * 32 + r] = m;
  lbuf[g * 32 + r] = lsum;
#pragma unroll
  for (int d = 0; d < 32; d++)
    ctxbuf[(g * 32 + r) * 32 + ((d + r) & 31)] = ctx[d];
  __syncthreads();
  int r2 = t & 31, dq = t >> 5;
  float M = -1e30f;
#pragma unroll
  for (int gg = 0; gg < 8; gg++) M = fmaxf(M, mbuf[gg * 32 + r2]);
  float wg[8]; float L = 0.f;
#pragma unroll
  for (int gg = 0; gg < 8; gg++) {
    wg[gg] = __expf(mbuf[gg * 32 + r2] - M);
    L += lbuf[gg * 32 + r2] * wg[gg];
  }
  float invL = 1.f / L;
  size_t base = (size_t)(b * S_ + qt * 32 + r2) * E_ + h * 32;
#pragma unroll
  for (int dd = 0; dd < 4; dd++) {
    int d = dq * 4 + dd;
    float o = 0.f;
#pragma unroll
    for (int gg = 0; gg < 8; gg++)
      o += ctxbuf[(gg * 32 + r2) * 32 + ((d + r2) & 31)] * wg[gg];
    o *= invL;
    short hi = f2bf(o);
    Chi[base + d] = hi;
    Clo[base + d] = f2bf(o - bf2f(hi));
  }
}

// ---------------------------------------------------------------------------
// conv_fused v8 = v7 + fragment-major W reads (w2p/w3p).
//   Wave fragment load: 64 lanes x 16B = 1 KB contiguous (was stride-768B
//   scatter, 25% line efficiency); w2p (32KB) + w3p (16KB) stay L1-resident
//   across the 4 resident blocks. Values bit-identical to w2bf/w3bf path.
// ---------------------------------------------------------------------------
__global__ __launch_bounds__(256, 4) void conv_fused_k(
    const float* __restrict__ lo, const float* __restrict__ G,
    const int* __restrict__ ids,
    const short* __restrict__ w2p, const short* __restrict__ w3p,
    const float* __restrict__ sc2, const float* __restrict__ sh2,
    const float* __restrict__ sc3, const float* __restrict__ sh3,
    const float* __restrict__ w4, const float* __restrict__ b4,
    float* __restrict__ out) {
  __shared__ __align__(16) short smem[17408];   // 34816 B (A tile, H2 overlay)
  __shared__ int lds_ids[128];
  int t = threadIdx.x;
  int bid = blockIdx.x;
  int b = bid >> 9;
  int n0 = (bid & 511) << 7;
  int w = t >> 6, l = t & 63;
  int quad = l >> 4, lr = l & 15;
  int mh = w & 1, chh = w >> 1;
  int ar = t >> 1, akh = (t & 1) * 64;
  const float* lob = &lo[((size_t)b * N_ + n0 + ar) * LD_ + akh];

  // ---- G fast-path loads (issued first; latency hides under staging) ----
  int id0 = ids[n0], id127 = ids[n0 + 127];
  bool uni = (id0 == id127);
  float gseed[4];
  {
    const float* gr = &G[((size_t)b * 256 + id0) * 128 + 64 * chh + lr];
#pragma unroll
    for (int ct = 0; ct < 4; ct++) gseed[ct] = gr[16 * ct];
  }
  if (t < 128) lds_ids[t] = ids[n0 + t];

  // ---- stage A full-K (64 floats/thread, two 32-float chunks) ----
  {
    float4 pf[8];
#pragma unroll
    for (int j = 0; j < 8; j++) pf[j] = *(const float4*)(lob + j * 4);
#pragma unroll
    for (int j = 0; j < 4; j++)
      *(s8v*)&smem[ar * 136 + akh + j * 8] = pack8(pf[2 * j], pf[2 * j + 1]);
#pragma unroll
    for (int j = 0; j < 8; j++) pf[j] = *(const float4*)(lob + 32 + j * 4);
#pragma unroll
    for (int j = 0; j < 4; j++)
      *(s8v*)&smem[ar * 136 + akh + 32 + j * 8] = pack8(pf[2 * j], pf[2 * j + 1]);
  }
  __syncthreads();   // #1

  // ---- seed acc2 with G residual (C-in). uni: 4 loads; else gather ----
  f32x4 acc2[4][4];
  if (uni) {
#pragma unroll
    for (int mt = 0; mt < 4; mt++)
#pragma unroll
      for (int ct = 0; ct < 4; ct++)
#pragma unroll
        for (int rg = 0; rg < 4; rg++)
          acc2[mt][ct][rg] = gseed[ct];
  } else {
#pragma unroll
    for (int mt = 0; mt < 4; mt++)
#pragma unroll
      for (int rg = 0; rg < 4; rg++) {
        int p = 64 * mh + 16 * mt + 4 * quad + rg;
        const float* gr = &G[((size_t)b * 256 + lds_ids[p]) * 128 + 64 * chh + lr];
#pragma unroll
        for (int ct = 0; ct < 4; ct++)
          acc2[mt][ct][rg] = gr[16 * ct];
      }
  }

  // ---- conv2: 128 pts x 128 ch, K=128; W2 frags fragment-major ----
#pragma unroll
  for (int ks = 0; ks < 4; ks++) {
    int ko = ks * 32 + quad * 8;
    s8v af[4], bfr[4];
#pragma unroll
    for (int mt = 0; mt < 4; mt++)
      af[mt] = *(const s8v*)&smem[(64 * mh + 16 * mt + lr) * 136 + ko];
#pragma unroll
    for (int ct = 0; ct < 4; ct++)
      bfr[ct] = *(const s8v*)&w2p[(((chh * 4 + ct) * 4 + ks) << 9) + l * 8];
#pragma unroll
    for (int mt = 0; mt < 4; mt++)
#pragma unroll
      for (int ct = 0; ct < 4; ct++)
        acc2[mt][ct] = __builtin_amdgcn_mfma_f32_16x16x32_bf16(af[mt], bfr[ct], acc2[mt][ct], 0, 0, 0);
  }
  __syncthreads();   // #2 (A reads done -> H2 may overlay)

  // ---- bn2 + relu -> H2 [128][136] ----
#pragma unroll
  for (int ct = 0; ct < 4; ct++) {
    int c = 64 * chh + 16 * ct + lr;
    float sc = sc2[c], sh = sh2[c];
#pragma unroll
    for (int mt = 0; mt < 4; mt++)
#pragma unroll
      for (int rg = 0; rg < 4; rg++) {
        int p = 64 * mh + 16 * mt + 4 * quad + rg;
        float z = acc2[mt][ct][rg] * sc + sh;
        smem[p * 136 + c] = f2bf(fmaxf(z, 0.f));
      }
  }
  __syncthreads();   // #3

  // ---- conv3: 128 pts x 64 ch, K=128; W3 frags fragment-major ----
  f32x4 acc3[2][4];
#pragma unroll
  for (int i = 0; i < 2; i++)
#pragma unroll
    for (int j = 0; j < 4; j++) acc3[i][j] = (f32x4)(0.f);
#pragma unroll
  for (int ks = 0; ks < 4; ks++) {
    int ko = ks * 32 + quad * 8;
    s8v af2[2], bf3[4];
#pragma unroll
    for (int mt = 0; mt < 2; mt++)
      af2[mt] = *(const s8v*)&smem[(32 * w + 16 * mt + lr) * 136 + ko];
#pragma unroll
    for (int ct = 0; ct < 4; ct++)
      bf3[ct] = *(const s8v*)&w3p[(((ct * 4) + ks) << 9) + l * 8];
#pragma unroll
    for (int mt = 0; mt < 2; mt++)
#pragma unroll
      for (int ct = 0; ct < 4; ct++)
        acc3[mt][ct] = __builtin_amdgcn_mfma_f32_16x16x32_bf16(af2[mt], bf3[ct], acc3[mt][ct], 0, 0, 0);
  }

  // ---- bn3 + relu + conv4, fully in-register (no barriers) ----
  float w4c0[4], w4c1[4], s3[4], b3sh[4];
#pragma unroll
  for (int ct = 0; ct < 4; ct++) {
    int c = 16 * ct + lr;
    s3[ct] = sc3[c]; b3sh[ct] = sh3[c];
    w4c0[ct] = w4[c];        // out-ch 0
    w4c1[ct] = w4[64 + c];   // out-ch 1
  }
  int c4s = lr & 1, rgs = (lr >> 1) & 3, mts = lr >> 3;   // this lane's output
  float myout = 0.f;
#pragma unroll
  for (int mt = 0; mt < 2; mt++)
#pragma unroll
    for (int rg = 0; rg < 4; rg++) {
      float p0 = 0.f, p1 = 0.f;
#pragma unroll
      for (int ct = 0; ct < 4; ct++) {
        float z = fmaxf(fmaf(acc3[mt][ct][rg], s3[ct], b3sh[ct]), 0.f);
        p0 = fmaf(z, w4c0[ct], p0);
        p1 = fmaf(z, w4c1[ct], p1);
      }
#pragma unroll
      for (int m = 1; m < 16; m <<= 1) {
        p0 += __shfl_xor(p0, m, 64);
        p1 += __shfl_xor(p1, m, 64);
      }
      bool mine = (mt == mts) && (rg == rgs);
      float pv = c4s ? p1 : p0;
      myout = mine ? pv : myout;
    }
  {
    int p = 32 * w + 16 * mts + 4 * quad + rgs;
    out[((size_t)b * NC_ + c4s) * N_ + n0 + p] = myout + b4[c4s];
  }
}

// ---------------------------------------------------------------------------
extern "C" void kernel_launch(void* const* d_in, const int* in_sizes, int n_in,
                              void* d_out, int out_size, void* d_ws, size_t ws_size,
                              hipStream_t stream) {
  const float* gl   = (const float*)d_in[0];
  const float* lo   = (const float*)d_in[1];
  const float* cen  = (const float*)d_in[2];
  const int*   npc  = (const int*)d_in[3];
  const float* fc1w = (const float*)d_in[4];
  const float* fc1b = (const float*)d_in[5];
  const float* fc2w = (const float*)d_in[6];
  const float* fc2b = (const float*)d_in[7];
  const float* ipw  = (const float*)d_in[8];
  const float* ipb  = (const float*)d_in[9];
  const float* opw  = (const float*)d_in[10];
  const float* opb  = (const float*)d_in[11];
  const float* w2   = (const float*)d_in[12];
  const float* b2   = (const float*)d_in[13];
  const float* g2   = (const float*)d_in[14];
  const float* be2  = (const float*)d_in[15];
  const float* mu2  = (const float*)d_in[16];
  const float* va2  = (const float*)d_in[17];
  const float* w3   = (const float*)d_in[18];
  const float* b3   = (const float*)d_in[19];
  const float* g3   = (const float*)d_in[20];
  const float* be3  = (const float*)d_in[21];
  const float* mu3  = (const float*)d_in[22];
  const float* va3  = (const float*)d_in[23];
  const float* w4   = (const float*)d_in[24];
  const float* b4   = (const float*)d_in[25];

  char* ws = (char*)d_ws;
  float* qkv  = (float*)(ws);                  // 3,145,728
  short* Xhi  = (short*)(ws + 3145728);        // 524,288
  short* Xlo  = (short*)(ws + 3670016);
  short* Chi  = (short*)(ws + 4194304);
  short* Clo  = (short*)(ws + 4718592);
  float* G    = (float*)(ws + 5242880);        // 524,288 (B,256,128) fp32
  short* iph  = (short*)(ws + 5767168);        // 393,216
  short* ipl  = (short*)(ws + 6160384);
  short* Mh   = (short*)(ws + 6553600);        // 65,536
  short* Ml   = (short*)(ws + 6684672);        // 65,536
  short* w2p  = (short*)(ws + 6815744);        // 32,768 (fragment-major)
  short* w3p  = (short*)(ws + 6914048);        // 16,384 (fragment-major)
  int*   ids  = (int*)  (ws + 6930432);        // 262,144
  float* sc2  = (float*)(ws + 7192576);
  float* sh2  = (float*)(ws + 7193088);
  float* sc3  = (float*)(ws + 7193600);
  float* sh3  = (float*)(ws + 7193856);
  float* g0v  = (float*)(ws + 7194112);        // 512
  float* out  = (float*)d_out;

  prep_k<<<2177, 256, 0, stream>>>(npc, ids, ipw, opw, opb, w2, w3,
                                   b2, g2, be2, mu2, va2,
                                   b3, g3, be3, mu3, va3,
                                   iph, ipl, Mh, Ml, g0v, w2p, w3p,
                                   sc2, sh2, sc3, sh3,
                                   gl, cen, fc1w, fc1b, fc2w, fc2b, Xhi, Xlo);
  gemm_x3_k<<<dim3(16, 12), 256, 0, stream>>>(Xhi, Xlo, iph, ipl, ipb,
                                              qkv, B_ * S_, 768, E_);
  attn_k<<<B_ * H_ * 8, 256, 0, stream>>>(qkv, Chi, Clo);
  gk_k<<<dim3(16, 4), 256, 0, stream>>>(Chi, Clo, Mh, Ml, g0v, G);
  conv_fused_k<<<B_ * (N_ / 128), 256, 0, stream>>>(
      lo, G, ids, w2p, w3p, sc2, sh2, sc3, sh3, w4, b4, out);
}